// Round 13
// baseline (2077.660 us; speedup 1.0000x reference)
//
#include <hip/hip_runtime.h>
#include <math.h>

typedef unsigned short u16;
typedef __bf16 bf16_t;
typedef bf16_t bf16x8 __attribute__((ext_vector_type(8)));
typedef float f32x4v __attribute__((ext_vector_type(4)));
typedef u16 u16x8 __attribute__((ext_vector_type(8)));
typedef u16 u16x4 __attribute__((ext_vector_type(4)));

__device__ inline u16 f2bf(float f){ __bf16 h=(__bf16)f; return __builtin_bit_cast(u16,h); }
__device__ inline float bf2f(u16 u){ unsigned int x=((unsigned int)u)<<16; return __builtin_bit_cast(float,x); }

#define GLD16(gp,lp) __builtin_amdgcn_global_load_lds( \
  (const __attribute__((address_space(1))) void*)(gp), \
  (__attribute__((address_space(3))) void*)(lp), 16, 0, 0)

#define MFMA_B16(a,b,c) __builtin_amdgcn_mfma_f32_16x16x32_bf16(a,b,c,0,0,0)
#define ALPHA_S 0.044194173824159216f

struct GP {
  const u16* A; int lda; long long sA1, sA2;
  const u16* B; int ldb; long long sB1, sB2;
  const float* bias; long long sb1, sb2, sbg;
  float* Cf; u16* Cb; int ldc; long long sC1, sC2;
  int M, N, K, Z2, epi, perm;
  float alpha;
};

__device__ inline float epiF(float v,int epi){
  if(epi==1) return fmaxf(v,0.f);
  if(epi==2) return 0.5f*v*(1.f+erff(v*0.70710678118654752f));
  return v;
}

// XCD-aware bijective block remap (m204): round-robin -> chunked, so each
// XCD owns a contiguous range of logical blocks (L2 panel reuse). Pure
// permutation: correctness independent of actual HW XCD assignment.
__device__ inline void xcd_remap(int& bx,int& by,int& bz){
  int gx=gridDim.x, gy=gridDim.y;
  int nwg=gx*gy*gridDim.z;
  int flat=blockIdx.x+gx*(blockIdx.y+gy*blockIdx.z);
  int q=nwg>>3, r=nwg&7;
  int xcd=flat&7, sub=flat>>3;
  int wg=(xcd<r? xcd*(q+1) : r*(q+1)+(xcd-r)*q)+sub;
  bx=wg%gx; int t2=wg/gx; by=t2%gy; bz=t2/gy;
}

// ---------------------------------------------------------------------------
// Small-tile kernel (128x128, 4 waves, BK=32, 3-buf depth-2 pipeline).
// Epilogue: R8-verified vectorized path (conflicts==0 measured). Don't touch.
// ---------------------------------------------------------------------------
__global__ __launch_bounds__(256) void gemm_bt(GP p){
  __shared__ u16 L[3*8192];
  int bx,by,bz; xcd_remap(bx,by,bz);
  const int z=bz, z1=z/p.Z2, z2=z-z1*p.Z2;
  const u16* __restrict__ Ab = p.A + z1*p.sA1 + z2*p.sA2;
  const u16* __restrict__ Bb = p.B + z1*p.sB1 + z2*p.sB2;
  const int tm=bx*128, tn=by*128;
  const int t=threadIdx.x, lane=t&63, wv=t>>6;
  const int wr=(wv>>1)*64, wc=(wv&1)*64;
  const int fr=lane&15, c16=lane>>4;

  long long aoff[2], boff[2];
  #pragma unroll
  for(int q=0;q<2;q++){
    int s=(wv*2+q)*64+lane;
    int r=s>>2;
    int col=((s&3)^((r>>1)&3))*8;
    int ga=tm+r; if(ga>p.M-1) ga=p.M-1;
    int gb=tn+r; if(gb>p.N-1) gb=p.N-1;
    aoff[q]=(long long)ga*p.lda+col;
    boff[q]=(long long)gb*p.ldb+col;
  }

  auto STAGE=[&](int tk,int buf){
    const long long kk=(long long)tk*32;
    u16* base=&L[buf*8192];
    #pragma unroll
    for(int q=0;q<2;q++){
      GLD16(Ab+aoff[q]+kk, base+(wv*2+q)*512);
      GLD16(Bb+boff[q]+kk, base+4096+(wv*2+q)*512);
    }
  };

  const int nt = p.K >> 5;
  f32x4v acc[4][4]={};

  STAGE(0,0);
  if(nt>1){
    STAGE(1,1);
    asm volatile("s_waitcnt vmcnt(4)" ::: "memory");
  } else {
    asm volatile("s_waitcnt vmcnt(0)" ::: "memory");
  }
  __builtin_amdgcn_s_barrier();
  __builtin_amdgcn_sched_barrier(0);

  for(int i=0;i<nt;++i){
    const int buf=i%3;
    if(i+2<nt) STAGE(i+2,(i+2)%3);
    const u16* Abuf=&L[buf*8192];
    const u16* Bbuf=&L[buf*8192+4096];
    bf16x8 af[4], bfv[4];
    #pragma unroll
    for(int m=0;m<4;m++){ int r=wr+16*m+fr; af[m]=*(const bf16x8*)&Abuf[r*32+((c16^((r>>1)&3))*8)]; }
    #pragma unroll
    for(int n=0;n<4;n++){ int r=wc+16*n+fr; bfv[n]=*(const bf16x8*)&Bbuf[r*32+((c16^((r>>1)&3))*8)]; }
    #pragma unroll
    for(int m=0;m<4;m++)
      #pragma unroll
      for(int n=0;n<4;n++)
        acc[m][n]=MFMA_B16(af[m],bfv[n],acc[m][n]);
    if(i+1<nt){
      if(i+2<nt) asm volatile("s_waitcnt vmcnt(4)" ::: "memory");
      else       asm volatile("s_waitcnt vmcnt(0)" ::: "memory");
      __builtin_amdgcn_s_barrier();
      __builtin_amdgcn_sched_barrier(0);
    }
  }

  const int rq=lane>>4;
  const long long cbase = z1*p.sC1 + z2*p.sC2;
  float* __restrict__ Cf = p.Cf? p.Cf+cbase : nullptr;
  u16*  __restrict__ Cbp = p.Cb? p.Cb+cbase : nullptr;

  const bool vec = (!p.perm) && (p.epi!=3) && ((p.N&63)==0) && !(Cf&&Cbp);
  if(vec){
    float bvn[4];
    #pragma unroll
    for(int n=0;n<4;n++){
      int gc=tn+wc+n*16+fr; if(gc>p.N-1) gc=p.N-1;
      bvn[n]=p.bias? p.bias[z1*p.sb1+z2*p.sb2+(long long)gc*p.sbg] : 0.f;
    }
    if(Cbp){
      u16* my=(u16*)L + wv*1024;
      #pragma unroll
      for(int m=0;m<4;m++){
        __syncthreads();
        #pragma unroll
        for(int n=0;n<4;n++){
          int pg=((n^rq)<<4)+fr;
          #pragma unroll
          for(int r=0;r<4;r++)
            my[(4*rq+r)*64+pg]=f2bf(epiF(acc[m][n][r]*p.alpha+bvn[n],p.epi));
        }
        __syncthreads();
        #pragma unroll
        for(int ps=0;ps<2;ps++){
          int row=ps*8+(lane>>3), h=lane&7;
          int grow=tm+wr+m*16+row, gc0=tn+wc+h*8;
          if(grow<p.M && gc0<p.N){
            int phys=(((h>>1)^(row>>2))<<4)+((h&1)<<3);
            *(u16x8*)&Cbp[(long long)grow*p.ldc+gc0]=*(const u16x8*)&my[row*64+phys];
          }
        }
      }
    } else {
      float* my=(float*)L + wv*1024;
      #pragma unroll
      for(int m=0;m<4;m++){
        __syncthreads();
        #pragma unroll
        for(int n=0;n<4;n++){
          int pg=((n^rq)<<4)+fr;
          #pragma unroll
          for(int r=0;r<4;r++)
            my[(4*rq+r)*64+pg]=epiF(acc[m][n][r]*p.alpha+bvn[n],p.epi);
        }
        __syncthreads();
        #pragma unroll
        for(int ps=0;ps<2;ps++){
          int row=ps*8+(lane>>3), h=lane&7;
          int grow=tm+wr+m*16+row, gc0=tn+wc+h*8;
          if(grow<p.M && gc0<p.N){
            int phys=(((h>>1)^(row>>2))<<4)+((h&1)<<3);
            *(float4*)&Cf[(long long)grow*p.ldc+gc0]  =*(const float4*)&my[row*64+phys];
            *(float4*)&Cf[(long long)grow*p.ldc+gc0+4]=*(const float4*)&my[row*64+phys+4];
          }
        }
      }
    }
    return;
  }

  #pragma unroll
  for(int m=0;m<4;m++){
    int grow0=tm+wr+16*m+4*rq;
    #pragma unroll
    for(int n=0;n<4;n++){
      int gcol=tn+wc+16*n+fr;
      if(gcol>=p.N) continue;
      float bv = p.bias? p.bias[z1*p.sb1+z2*p.sb2+(long long)gcol*p.sbg] : 0.f;
      #pragma unroll
      for(int r=0;r<4;r++){
        int grow=grow0+r;
        if(grow>=p.M) continue;
        float v=acc[m][n][r]*p.alpha+bv;
        if(p.epi==1) v=fmaxf(v,0.f);
        else if(p.epi==2) v=0.5f*v*(1.f+erff(v*0.70710678118654752f));
        else if(p.epi==3){
          int tt=grow&511;
          float ang=(float)tt*expf((float)(gcol&~1)*(-0.017988946039015967f));
          v += (gcol&1)? cosf(ang) : sinf(ang);
        }
        long long ci;
        if(p.perm) ci = ((long long)((grow&31)*101 + (grow>>5)))*100 + gcol;
        else       ci = (long long)grow*p.ldc+gcol;
        if(Cf) Cf[ci]=v;
        if(Cbp) Cbp[ci]=f2bf(v);
      }
    }
  }
}

// ---------------------------------------------------------------------------
// Fused expert-S kernel: one block per (e,b). K-loop identical to gemm_bt.
// Epilogue: S f32 -> LDS (pitch 132, 16B-aligned rows), row softmax with
// float4 LDS ops, column mean -> abar[z][128].
// ---------------------------------------------------------------------------
__global__ __launch_bounds__(256) void gemm_sfused(
    const u16* __restrict__ Pm, const u16* __restrict__ mem,
    const float* __restrict__ U, float* __restrict__ abar){
  __shared__ float Sl[128*132];           // 67.6 KB; low 48KB aliased as staging
  u16* L=(u16*)Sl;
  const int z=blockIdx.x, e=z>>5, b=z&31;
  const u16* __restrict__ Ab = Pm + (long long)e*2097152 + (long long)b*65536;
  const u16* __restrict__ Bb = mem + (long long)b*65536;
  const int t=threadIdx.x, lane=t&63, wv=t>>6;
  const int wr=(wv>>1)*64, wc=(wv&1)*64;
  const int fr=lane&15, c16=lane>>4;

  long long aoff[2], boff[2];
  #pragma unroll
  for(int q=0;q<2;q++){
    int s=(wv*2+q)*64+lane;
    int r=s>>2;
    int col=((s&3)^((r>>1)&3))*8;
    aoff[q]=(long long)r*512+col;
    boff[q]=(long long)r*512+col;
  }
  auto STAGE=[&](int tk,int buf){
    const long long kk=(long long)tk*32;
    u16* base=&L[buf*8192];
    #pragma unroll
    for(int q=0;q<2;q++){
      GLD16(Ab+aoff[q]+kk, base+(wv*2+q)*512);
      GLD16(Bb+boff[q]+kk, base+4096+(wv*2+q)*512);
    }
  };

  f32x4v acc[4][4]={};
  STAGE(0,0);
  STAGE(1,1);
  asm volatile("s_waitcnt vmcnt(4)" ::: "memory");
  __builtin_amdgcn_s_barrier();
  __builtin_amdgcn_sched_barrier(0);

  for(int i=0;i<16;++i){
    const int buf=i%3;
    if(i+2<16) STAGE(i+2,(i+2)%3);
    const u16* Abuf=&L[buf*8192];
    const u16* Bbuf=&L[buf*8192+4096];
    bf16x8 af[4], bfv[4];
    #pragma unroll
    for(int m=0;m<4;m++){ int r=wr+16*m+fr; af[m]=*(const bf16x8*)&Abuf[r*32+((c16^((r>>1)&3))*8)]; }
    #pragma unroll
    for(int n=0;n<4;n++){ int r=wc+16*n+fr; bfv[n]=*(const bf16x8*)&Bbuf[r*32+((c16^((r>>1)&3))*8)]; }
    #pragma unroll
    for(int m=0;m<4;m++)
      #pragma unroll
      for(int n=0;n<4;n++)
        acc[m][n]=MFMA_B16(af[m],bfv[n],acc[m][n]);
    if(i+1<16){
      if(i+2<16) asm volatile("s_waitcnt vmcnt(4)" ::: "memory");
      else       asm volatile("s_waitcnt vmcnt(0)" ::: "memory");
      __builtin_amdgcn_s_barrier();
      __builtin_amdgcn_sched_barrier(0);
    }
  }

  const int rq=lane>>4;
  float bvn[4];
  #pragma unroll
  for(int n=0;n<4;n++){
    int col=wc+n*16+fr;
    bvn[n]=U[((long long)(b*128+col))*101+e];
  }
  __syncthreads();                        // staging LDS reads done before alias
  #pragma unroll
  for(int m=0;m<4;m++)
    #pragma unroll
    for(int n=0;n<4;n++){
      int col=wc+n*16+fr;
      #pragma unroll
      for(int r=0;r<4;r++){
        int row=wr+m*16+4*rq+r;
        Sl[row*132+col]=acc[m][n][r]*ALPHA_S+bvn[n];
      }
    }
  __syncthreads();
  {
    int row=t>>1, h=t&1;
    float4* p4=(float4*)&Sl[row*132+h*64];
    float mx=-3.0e38f;
    #pragma unroll 4
    for(int j=0;j<16;j++){
      float4 v=p4[j];
      mx=fmaxf(mx,fmaxf(fmaxf(v.x,v.y),fmaxf(v.z,v.w)));
    }
    mx=fmaxf(mx,__shfl_xor(mx,1));
    float s=0.f;
    #pragma unroll 4
    for(int j=0;j<16;j++){
      float4 v=p4[j];
      v.x=__expf(v.x-mx); v.y=__expf(v.y-mx);
      v.z=__expf(v.z-mx); v.w=__expf(v.w-mx);
      s+=v.x+v.y+v.z+v.w;
      p4[j]=v;
    }
    s+=__shfl_xor(s,1);
    float inv=1.f/s;
    #pragma unroll 4
    for(int j=0;j<16;j++){
      float4 v=p4[j];
      v.x*=inv; v.y*=inv; v.z*=inv; v.w*=inv;
      p4[j]=v;
    }
  }
  __syncthreads();
  if(t<128){
    float s=0.f;
    for(int r=0;r<128;r++) s+=Sl[r*132+t];
    abar[(long long)z*128+t]=s*(1.f/128.f);
  }
}

// ---------------------------------------------------------------------------
// 8-phase big kernel: 256x256 tile, BK=64, 512 threads (8 waves 2Mx4N).
// K-loop + R8-verified epilogue (conflicts==0 measured). Don't touch.
// ---------------------------------------------------------------------------
__global__ __launch_bounds__(512) void gemm_big8(GP p){
  __shared__ u16 L[65536];   // 128 KB
  int bx,by,bz; xcd_remap(bx,by,bz);
  const int z=bz, z1=z/p.Z2, z2=z-z1*p.Z2;
  const u16* __restrict__ Ab = p.A + z1*p.sA1 + z2*p.sA2;
  const u16* __restrict__ Bb = p.B + z1*p.sB1 + z2*p.sB2;
  const int tm=bx*256, tn=by*256;
  const int t=threadIdx.x, lane=t&63, wv=t>>6;
  const int wr2=(wv>>2)*128, wc2=(wv&3)*64;
  const int fr=lane&15, c16=lane>>4;

  long long aoff[2], boff[2];
  {
    int rr=t>>2, cs=((t&3)^((t>>3)&3))*8;
    #pragma unroll
    for(int q=0;q<2;q++){
      int ga=tm+q*128+rr; if(ga>p.M-1) ga=p.M-1;
      int gb=tn+q*128+rr; if(gb>p.N-1) gb=p.N-1;
      aoff[q]=(long long)ga*p.lda+cs;
      boff[q]=(long long)gb*p.ldb+cs;
    }
  }

  auto STAGE_A=[&](int kt,int d,int ks){
    const long long k0=(long long)kt*64+ks*32;
    u16* dst=&L[d*16384+ks*8192];
    GLD16(Ab+aoff[0]+k0, dst+t*8);
    GLD16(Ab+aoff[1]+k0, dst+4096+t*8);
  };
  auto STAGE_B=[&](int kt,int d,int ks){
    const long long k0=(long long)kt*64+ks*32;
    u16* dst=&L[32768+d*16384+ks*8192];
    GLD16(Bb+boff[0]+k0, dst+t*8);
    GLD16(Bb+boff[1]+k0, dst+4096+t*8);
  };
  auto LDA_=[&](int d,int ks,int m)->bf16x8{
    int R=wr2+m*16+fr;
    return *(const bf16x8*)&L[d*16384+ks*8192+R*32+((c16^((R>>1)&3))*8)];
  };
  auto LDB_=[&](int d,int ks,int n)->bf16x8{
    int R=wc2+n*16+fr;
    return *(const bf16x8*)&L[32768+d*16384+ks*8192+R*32+((c16^((R>>1)&3))*8)];
  };

  const int ntk=p.K>>6;
  f32x4v acc[8][4]={};
  bf16x8 af[8], bq0, bq1, bq2, bq3;

  STAGE_A(0,0,0); STAGE_B(0,0,0); STAGE_A(0,0,1); STAGE_B(0,0,1);
  asm volatile("s_waitcnt vmcnt(4)" ::: "memory");
  __builtin_amdgcn_s_barrier();
  __builtin_amdgcn_sched_barrier(0);

  for(int kt=0;kt<ntk;++kt){
    const int d=kt&1, nd=d^1;
    const bool nxt=(kt+1<ntk);
    // phase 1
    #pragma unroll
    for(int m=0;m<8;m++) af[m]=LDA_(d,0,m);
    bq0=LDB_(d,0,0); bq1=LDB_(d,0,1);
    if(nxt) STAGE_A(kt+1,nd,0);
    __builtin_amdgcn_s_barrier();
    asm volatile("s_waitcnt lgkmcnt(0)" ::: "memory");
    __builtin_amdgcn_sched_barrier(0);
    __builtin_amdgcn_s_setprio(1);
    #pragma unroll
    for(int m=0;m<8;m++){
      acc[m][0]=MFMA_B16(af[m],bq0,acc[m][0]);
      acc[m][1]=MFMA_B16(af[m],bq1,acc[m][1]);
    }
    __builtin_amdgcn_s_setprio(0);
    __builtin_amdgcn_s_barrier();
    // phase 2
    bq2=LDB_(d,0,2); bq3=LDB_(d,0,3);
    if(nxt) STAGE_B(kt+1,nd,0);
    __builtin_amdgcn_s_barrier();
    asm volatile("s_waitcnt lgkmcnt(0)" ::: "memory");
    __builtin_amdgcn_sched_barrier(0);
    __builtin_amdgcn_s_setprio(1);
    #pragma unroll
    for(int m=0;m<8;m++){
      acc[m][2]=MFMA_B16(af[m],bq2,acc[m][2]);
      acc[m][3]=MFMA_B16(af[m],bq3,acc[m][3]);
    }
    __builtin_amdgcn_s_setprio(0);
    if(nxt) asm volatile("s_waitcnt vmcnt(4)" ::: "memory");
    else    asm volatile("s_waitcnt vmcnt(0)" ::: "memory");
    __builtin_amdgcn_s_barrier();
    __builtin_amdgcn_sched_barrier(0);
    // phase 3
    #pragma unroll
    for(int m=0;m<8;m++) af[m]=LDA_(d,1,m);
    bq0=LDB_(d,1,0); bq1=LDB_(d,1,1);
    if(nxt) STAGE_A(kt+1,nd,1);
    __builtin_amdgcn_s_barrier();
    asm volatile("s_waitcnt lgkmcnt(0)" ::: "memory");
    __builtin_amdgcn_sched_barrier(0);
    __builtin_amdgcn_s_setprio(1);
    #pragma unroll
    for(int m=0;m<8;m++){
      acc[m][0]=MFMA_B16(af[m],bq0,acc[m][0]);
      acc[m][1]=MFMA_B16(af[m],bq1,acc[m][1]);
    }
    __builtin_amdgcn_s_setprio(0);
    __builtin_amdgcn_s_barrier();
    // phase 4
    bq2=LDB_(d,1,2); bq3=LDB_(d,1,3);
    if(nxt) STAGE_B(kt+1,nd,1);
    __builtin_amdgcn_s_barrier();
    asm volatile("s_waitcnt lgkmcnt(0)" ::: "memory");
    __builtin_amdgcn_sched_barrier(0);
    __builtin_amdgcn_s_setprio(1);
    #pragma unroll
    for(int m=0;m<8;m++){
      acc[m][2]=MFMA_B16(af[m],bq2,acc[m][2]);
      acc[m][3]=MFMA_B16(af[m],bq3,acc[m][3]);
    }
    __builtin_amdgcn_s_setprio(0);
    if(nxt) asm volatile("s_waitcnt vmcnt(4)" ::: "memory");
    __builtin_amdgcn_s_barrier();
    __builtin_amdgcn_sched_barrier(0);
  }

  const int rq=lane>>4;
  const long long cbase = z1*p.sC1 + z2*p.sC2;
  float* __restrict__ Cf = p.Cf? p.Cf+cbase : nullptr;
  u16*  __restrict__ Cbp = p.Cb? p.Cb+cbase : nullptr;

  const bool vec = (!p.perm) && (p.epi!=3) && ((p.N&63)==0) && !(Cf&&Cbp);
  if(vec){
    float bvn[4];
    #pragma unroll
    for(int n=0;n<4;n++){
      int gc=tn+wc2+n*16+fr; if(gc>p.N-1) gc=p.N-1;
      bvn[n]=p.bias? p.bias[z1*p.sb1+z2*p.sb2+(long long)gc*p.sbg] : 0.f;
    }
    if(Cbp){
      u16* my=(u16*)L + wv*1024;
      #pragma unroll
      for(int m=0;m<8;m++){
        __syncthreads();
        #pragma unroll
        for(int n=0;n<4;n++){
          int pg=((n^rq)<<4)+fr;
          #pragma unroll
          for(int r=0;r<4;r++)
            my[(4*rq+r)*64+pg]=f2bf(epiF(acc[m][n][r]*p.alpha+bvn[n],p.epi));
        }
        __syncthreads();
        #pragma unroll
        for(int ps=0;ps<2;ps++){
          int row=ps*8+(lane>>3), h=lane&7;
          int grow=tm+wr2+m*16+row, gc0=tn+wc2+h*8;
          if(grow<p.M && gc0<p.N){
            int phys=(((h>>1)^(row>>2))<<4)+((h&1)<<3);
            *(u16x8*)&Cbp[(long long)grow*p.ldc+gc0]=*(const u16x8*)&my[row*64+phys];
          }
        }
      }
    } else {
      float* my=(float*)L + wv*1024;
      #pragma unroll
      for(int m=0;m<8;m++){
        __syncthreads();
        #pragma unroll
        for(int n=0;n<4;n++){
          int pg=((n^rq)<<4)+fr;
          #pragma unroll
          for(int r=0;r<4;r++)
            my[(4*rq+r)*64+pg]=epiF(acc[m][n][r]*p.alpha+bvn[n],p.epi);
        }
        __syncthreads();
        #pragma unroll
        for(int ps=0;ps<2;ps++){
          int row=ps*8+(lane>>3), h=lane&7;
          int grow=tm+wr2+m*16+row, gc0=tn+wc2+h*8;
          if(grow<p.M && gc0<p.N){
            int phys=(((h>>1)^(row>>2))<<4)+((h&1)<<3);
            *(float4*)&Cf[(long long)grow*p.ldc+gc0]  =*(const float4*)&my[row*64+phys];
            *(float4*)&Cf[(long long)grow*p.ldc+gc0+4]=*(const float4*)&my[row*64+phys+4];
          }
        }
      }
    }
    return;
  }

  #pragma unroll
  for(int m=0;m<8;m++){
    int grow0=tm+wr2+m*16+4*rq;
    #pragma unroll
    for(int n=0;n<4;n++){
      int gcol=tn+wc2+n*16+fr;
      if(gcol>=p.N) continue;
      float bv = p.bias? p.bias[z1*p.sb1+z2*p.sb2+gcol] : 0.f;
      #pragma unroll
      for(int r=0;r<4;r++){
        int grow=grow0+r;
        if(grow>=p.M) continue;
        float v=epiF(acc[m][n][r]*p.alpha+bv,p.epi);
        long long ci=(long long)grow*p.ldc+gcol;
        if(Cf) Cf[ci]=v;
        if(Cbp) Cbp[ci]=f2bf(v);
      }
    }
  }
}

// ---------------- row softmax over 512 cols, bf16 in-place -----------------
__global__ __launch_bounds__(256) void softmax512b(u16* __restrict__ S, int nrows){
  int row=blockIdx.x*4+(threadIdx.x>>6);
  if(row>=nrows) return;
  int lane=threadIdx.x&63;
  u16* p=S+(long long)row*512;
  u16x8 raw=*(u16x8*)&p[lane*8];
  float f[8];
  #pragma unroll
  for(int j=0;j<8;j++) f[j]=bf2f(raw[j]);
  float m=f[0];
  #pragma unroll
  for(int j=1;j<8;j++) m=fmaxf(m,f[j]);
  #pragma unroll
  for(int off=32;off;off>>=1) m=fmaxf(m,__shfl_xor(m,off));
  float s=0.f;
  #pragma unroll
  for(int j=0;j<8;j++){ f[j]=__expf(f[j]-m); s+=f[j]; }
  #pragma unroll
  for(int off=32;off;off>>=1) s+=__shfl_xor(s,off);
  float inv=1.f/s;
  u16x8 o;
  #pragma unroll
  for(int j=0;j<8;j++) o[j]=f2bf(f[j]*inv);
  *(u16x8*)&p[lane*8]=o;
}

// ------- LN rows of 512: y = LN(x [+res]) * g + b ; outputs f32/bf16 -------
__global__ __launch_bounds__(256) void ln512(
    const float* __restrict__ x, const float* __restrict__ res,
    const float* __restrict__ g, const float* __restrict__ bb, int pergroup,
    float* __restrict__ outf, u16* __restrict__ outb, int nrows)
{
  int row=blockIdx.x*4+(threadIdx.x>>6);
  if(row>=nrows) return;
  int lane=threadIdx.x&63;
  const float4* xp=(const float4*)(x+(long long)row*512);
  float4 v0=xp[lane], v1=xp[lane+64];
  if(res){
    const float4* rp=(const float4*)(res+(long long)row*512);
    float4 w0=rp[lane], w1=rp[lane+64];
    v0.x+=w0.x; v0.y+=w0.y; v0.z+=w0.z; v0.w+=w0.w;
    v1.x+=w1.x; v1.y+=w1.y; v1.z+=w1.z; v1.w+=w1.w;
  }
  float s=v0.x+v0.y+v0.z+v0.w+v1.x+v1.y+v1.z+v1.w;
  #pragma unroll
  for(int off=32;off;off>>=1) s+=__shfl_xor(s,off);
  float mu=s*(1.f/512.f);
  float q=(v0.x-mu)*(v0.x-mu)+(v0.y-mu)*(v0.y-mu)+(v0.z-mu)*(v0.z-mu)+(v0.w-mu)*(v0.w-mu)
        +(v1.x-mu)*(v1.x-mu)+(v1.y-mu)*(v1.y-mu)+(v1.z-mu)*(v1.z-mu)+(v1.w-mu)*(v1.w-mu);
  #pragma unroll
  for(int off=32;off;off>>=1) q+=__shfl_xor(q,off);
  float rstd=rsqrtf(q*(1.f/512.f)+1e-5f);
  long long go = pergroup? (long long)(row>>5)*512 : 0;
  float4 g0=((const float4*)(g+go))[lane],  g1=((const float4*)(g+go))[lane+64];
  float4 b0=((const float4*)(bb+go))[lane], b1=((const float4*)(bb+go))[lane+64];
  float4 o0,o1;
  o0.x=(v0.x-mu)*rstd*g0.x+b0.x; o0.y=(v0.y-mu)*rstd*g0.y+b0.y;
  o0.z=(v0.z-mu)*rstd*g0.z+b0.z; o0.w=(v0.w-mu)*rstd*g0.w+b0.w;
  o1.x=(v1.x-mu)*rstd*g1.x+b1.x; o1.y=(v1.y-mu)*rstd*g1.y+b1.y;
  o1.z=(v1.z-mu)*rstd*g1.z+b1.z; o1.w=(v1.w-mu)*rstd*g1.w+b1.w;
  if(outf){
    ((float4*)(outf+(long long)row*512))[lane]=o0;
    ((float4*)(outf+(long long)row*512))[lane+64]=o1;
  }
  if(outb){
    u16x4 h0,h1;
    h0[0]=f2bf(o0.x); h0[1]=f2bf(o0.y); h0[2]=f2bf(o0.z); h0[3]=f2bf(o0.w);
    h1[0]=f2bf(o1.x); h1[1]=f2bf(o1.y); h1[2]=f2bf(o1.z); h1[3]=f2bf(o1.w);
    ((u16x4*)(outb+(long long)row*512))[lane]=h0;
    ((u16x4*)(outb+(long long)row*512))[lane+64]=h1;
  }
}

// --------- transpose V slice of enc QKV (bf16), all 32 batches -------------
__global__ __launch_bounds__(256) void vtransb(const u16* __restrict__ qkv,
                                               u16* __restrict__ Vt){
  __shared__ u16 tile[64][72];
  int tt=blockIdx.x, h=blockIdx.y, zb=blockIdx.z;
  int t=threadIdx.x;
  int i=t>>2, j0=(t&3)*16;
  const u16* src = qkv + ((long long)(zb*512 + tt*64 + i))*1536 + 1024 + h*64 + j0;
  *(u16x8*)&tile[i][j0]   = *(const u16x8*)&src[0];
  *(u16x8*)&tile[i][j0+8] = *(const u16x8*)&src[8];
  __syncthreads();
  int j=t>>2, i0=(t&3)*16;
  u16 tmp[16];
  #pragma unroll
  for(int c=0;c<16;c++) tmp[c]=tile[i0+c][j];
  u16* dst = Vt + ((long long)((zb*8+h)*64 + j))*512 + tt*64 + i0;
  *(u16x8*)&dst[0]=*(u16x8*)&tmp[0];
  *(u16x8*)&dst[8]=*(u16x8*)&tmp[8];
}

// ------ transpose-convert [512,512] f32 tiles -> bf16 transposed -----------
__global__ __launch_bounds__(256) void trcvtb(const float* __restrict__ src,
                                              u16* __restrict__ dst){
  __shared__ float tile[64][65];
  int bi=blockIdx.x, bj=blockIdx.y, z=blockIdx.z;
  int e=z>>1, half=z&1;
  const float* s = src + (long long)e*786432 + half*262144;
  int t=threadIdx.x;
  int i=t>>2, j0=(t&3)*16;
  const float* sp = s + (long long)(bi*64+i)*512 + bj*64 + j0;
  #pragma unroll
  for(int c=0;c<4;c++){
    float4 v=((const float4*)sp)[c];
    tile[i][j0+4*c+0]=v.x; tile[i][j0+4*c+1]=v.y;
    tile[i][j0+4*c+2]=v.z; tile[i][j0+4*c+3]=v.w;
  }
  __syncthreads();
  int j=t>>2, i0=(t&3)*16;
  u16* d = dst + (long long)z*262144 + (long long)(bj*64+j)*512 + bi*64 + i0;
  u16x8 o0,o1;
  #pragma unroll
  for(int c=0;c<8;c++){ o0[c]=f2bf(tile[i0+c][j]); o1[c]=f2bf(tile[i0+8+c][j]); }
  *(u16x8*)&d[0]=o0; *(u16x8*)&d[8]=o1;
}

// ---------------- im2col for conv1d k=3 pad=1 (bf16 in/out) ----------------
__global__ __launch_bounds__(256) void im2col3b(const u16* __restrict__ in,
                                                u16* __restrict__ out,
                                                int Tlen, long long n8){
  long long idx=(long long)blockIdx.x*256+threadIdx.x;
  if(idx>=n8) return;
  int i8=(int)(idx&63); long long s=idx>>6;
  int dt=(int)(s%3); long long bt=s/3;
  int tt=(int)(bt%Tlen); int b=(int)(bt/Tlen);
  int tsrc=tt+dt-1;
  u16x8 v={0,0,0,0,0,0,0,0};
  if(tsrc>=0 && tsrc<Tlen) v=*(const u16x8*)&in[((long long)(b*Tlen+tsrc))*512 + i8*8];
  *(u16x8*)&out[idx*8]=v;
}

__global__ __launch_bounds__(256) void wrepackb(const float* __restrict__ w,
                                                u16* __restrict__ out){
  int idx=blockIdx.x*256+threadIdx.x;
  if(idx>=512*1536) return;
  int o=idx/1536; int rem=idx-o*1536;
  int dt=rem/512; int i=rem-dt*512;
  out[idx]=f2bf(w[((long long)o*512+i)*3+dt]);
}

// ------------- avgpool2 over time: f32 in -> bf16 out (4-wide) -------------
__global__ __launch_bounds__(256) void pool2b(const float* __restrict__ in,
                                              u16* __restrict__ out,
                                              int Tlen, long long n4){
  long long idx=(long long)blockIdx.x*256+threadIdx.x;
  if(idx>=n4) return;
  int c=(int)((idx&127)*4); long long s=idx>>7;
  int half=Tlen/2;
  int tp=(int)(s%half); int b=(int)(s/half);
  const float* p=in+((long long)(b*Tlen+2*tp))*512+c;
  float4 a=*(const float4*)p, d=*(const float4*)(p+512);
  u16x4 o;
  o[0]=f2bf(0.5f*(a.x+d.x)); o[1]=f2bf(0.5f*(a.y+d.y));
  o[2]=f2bf(0.5f*(a.z+d.z)); o[3]=f2bf(0.5f*(a.w+d.w));
  *(u16x4*)&out[(s*512)+c]=o;
}

// ---------------- flat f32 -> bf16 convert (8-wide) ------------------------
__global__ __launch_bounds__(256) void cvt_bf16(const float* __restrict__ in,
                                                u16* __restrict__ out, long long n8){
  long long i=(long long)blockIdx.x*256+threadIdx.x;
  if(i>=n8) return;
  const float4* p=(const float4*)(in+i*8);
  float4 a=p[0], b=p[1];
  u16x8 o;
  o[0]=f2bf(a.x); o[1]=f2bf(a.y); o[2]=f2bf(a.z); o[3]=f2bf(a.w);
  o[4]=f2bf(b.x); o[5]=f2bf(b.y); o[6]=f2bf(b.z); o[7]=f2bf(b.w);
  *(u16x8*)(out+i*8)=o;
}

// -------- strided chunk convert: 101 chunks of 262144 from stride 786432 ---
__global__ __launch_bounds__(256) void cvt_wv(const float* __restrict__ in,
                                              u16* __restrict__ out, long long n8){
  long long idx=(long long)blockIdx.x*256+threadIdx.x;
  if(idx>=n8) return;
  int e=(int)(idx>>15); long long r8=idx&32767;
  const float* p=in+(long long)e*786432+524288+r8*8;
  float4 a=((const float4*)p)[0], b=((const float4*)p)[1];
  u16x8 o;
  o[0]=f2bf(a.x); o[1]=f2bf(a.y); o[2]=f2bf(a.z); o[3]=f2bf(a.w);
  o[4]=f2bf(b.x); o[5]=f2bf(b.y); o[6]=f2bf(b.z); o[7]=f2bf(b.w);
  *(u16x8*)(out+idx*8)=o;
}

// -------- pad-convert rows: [rows,ks] f32 -> [rows,kd] bf16 (zero pad) -----
__global__ __launch_bounds__(256) void cvt_pad(const float* __restrict__ in,
                                               u16* __restrict__ out,
                                               int rows, int ks, int kd){
  long long idx=(long long)blockIdx.x*256+threadIdx.x;
  if(idx>=(long long)rows*kd) return;
  int r=(int)(idx/kd), c=(int)(idx-(long long)r*kd);
  out[idx]=(c<ks)? f2bf(in[(long long)r*ks+c]) : (u16)0;
}

// ---- per (b,e): w = abar@mem_b + pos_e (bf16) — softmax already fused -----
__global__ __launch_bounds__(256) void expert_reduce2(
    const float* __restrict__ abar, const u16* __restrict__ mem,
    const float* __restrict__ pos, u16* __restrict__ wout)
{
  int b=blockIdx.x, e=blockIdx.y;
  int t=threadIdx.x;
  __shared__ float abf[128];
  if(t<128) abf[t]=abar[((long long)(e*32+b))*128+t];
  __syncthreads();
  float c0=0.f, c1=0.f;
  const u16* mb = mem + (long long)b*65536;
  for(int k=0;k<128;++k){
    float a=abf[k];
    c0+=a*bf2f(mb[k*512+t]);
    c1+=a*bf2f(mb[k*512+t+256]);
  }
  c0+=pos[(long long)e*512+t]; c1+=pos[(long long)e*512+t+256];
  u16* o=wout+((long long)e*32+b)*512;
  o[t]=f2bf(c0); o[t+256]=f2bf(c1);
}

// ---------------------------------------------------------------------------
static inline int ceildiv(int a,int b){return (a+b-1)/b;}

static GP mkGP(const u16* A,int lda,long long sA1,long long sA2,
  const u16* B,int ldb,long long sB1,long long sB2,
  const float* bias,long long sb1,long long sb2,
  float* Cf,u16* Cb,int ldc,long long sC1,long long sC2,
  int M,int N,int K,int Z2,int epi,float alpha,long long sbg,int perm){
  GP p;
  p.A=A; p.lda=lda; p.sA1=sA1; p.sA2=sA2;
  p.B=B; p.ldb=ldb; p.sB1=sB1; p.sB2=sB2;
  p.bias=bias; p.sb1=sb1; p.sb2=sb2; p.sbg=sbg;
  p.Cf=Cf; p.Cb=Cb; p.ldc=ldc; p.sC1=sC1; p.sC2=sC2;
  p.M=M; p.N=N; p.K=K; p.Z2=Z2; p.epi=epi; p.perm=perm; p.alpha=alpha;
  return p;
}

static void gemmB(hipStream_t s,
  const u16* A,int lda,long long sA1,long long sA2,
  const u16* B,int ldb,long long sB1,long long sB2,
  const float* bias,long long sb1,long long sb2,
  float* Cf,u16* Cb,int ldc,long long sC1,long long sC2,
  int M,int N,int K,int Z,int Z2,int epi,float alpha,
  long long sbg=1,int perm=0){
  GP p=mkGP(A,lda,sA1,sA2,B,ldb,sB1,sB2,bias,sb1,sb2,Cf,Cb,ldc,sC1,sC2,M,N,K,Z2,epi,alpha,sbg,perm);
  dim3 g(ceildiv(M,128), ceildiv(N,128), Z);
  gemm_bt<<<g, dim3(256), 0, s>>>(p);
}

static void gemmBig(hipStream_t s,
  const u16* A,int lda,long long sA1,long long sA2,
  const u16* B,int ldb,long long sB1,long long sB2,
  const float* bias,long long sb1,long long sb2,
  float* Cf,u16* Cb,int ldc,long long sC1,long long sC2,
  int M,int N,int K,int Z,int Z2,int epi,float alpha){
  GP p=mkGP(A,lda,sA1,sA2,B,ldb,sB1,sB2,bias,sb1,sb2,Cf,Cb,ldc,sC1,sC2,M,N,K,Z2,epi,alpha,1,0);
  dim3 g(ceildiv(M,256), ceildiv(N,256), Z);
  gemm_big8<<<g, dim3(512), 0, s>>>(p);
}

static inline void cvt(hipStream_t s, const float* in, u16* out, long long n){
  long long n8=n/8;
  cvt_bf16<<<(int)((n8+255)/256),256,0,s>>>(in,out,n8);
}

extern "C" void kernel_launch(void* const* d_in, const int* in_sizes, int n_in,
                              void* d_out, int out_size, void* d_ws, size_t ws_size,
                              hipStream_t stream) {
  (void)in_sizes; (void)n_in; (void)out_size;
  const float* poses=(const float*)d_in[0];
  const float* W_in =(const float*)d_in[1];
  const float* b_in =(const float*)d_in[2];
  const float* eq_w =(const float*)d_in[3];
  const float* eq_b =(const float*)d_in[4];
  const float* eo_w =(const float*)d_in[5];
  const float* eo_b =(const float*)d_in[6];
  const float* ef1_w=(const float*)d_in[7];
  const float* ef1_b=(const float*)d_in[8];
  const float* ef2_w=(const float*)d_in[9];
  const float* ef2_b=(const float*)d_in[10];
  const float* en1_g=(const float*)d_in[11];
  const float* en1_b=(const float*)d_in[12];
  const float* en2_g=(const float*)d_in[13];
  const float* en2_b=(const float*)d_in[14];
  const float* c1_w =(const float*)d_in[15];
  const float* c1_b =(const float*)d_in[16];
  const float* c2_w =(const float*)d_in[17];
  const float* c2_b =(const float*)d_in[18];
  const float* mlp_w=(const float*)d_in[19];
  const float* mlp_b=(const float*)d_in[20];
  const float* xp_pos  =(const float*)d_in[21];
  const float* xp_qkv_w=(const float*)d_in[22];
  const float* xp_qkv_b=(const float*)d_in[23];
  const float* xp_o_w  =(const float*)d_in[24];
  const float* xp_o_b  =(const float*)d_in[25];
  const float* xp_n_g  =(const float*)d_in[26];
  const float* xp_n_b  =(const float*)d_in[27];
  const float* xp_l_w  =(const float*)d_in[28];
  const float* xp_l_b  =(const float*)d_in[29];
  const float* fn_g =(const float*)d_in[30];
  const float* fn_b =(const float*)d_in[31];
  const float* hd_w =(const float*)d_in[32];
  const float* hd_b =(const float*)d_in[33];
  float* out=(float*)d_out;

  float* ws=(float*)d_ws;
  size_t off=0;
  auto alloc=[&](size_t n)->float*{ float* p=ws+off; off+=(n+255)&~(size_t)255; return p; };
  float* RA = alloc(137760768);   // encoder-phase / expert-phase union
  float* RB = alloc(84381184);    // persistent converted weights
  float* RC = alloc(5849088);     // cross-phase (gmem, pools, w, cmean)
  if(off*sizeof(float) > ws_size) return;  // ws too small: bail (fails loudly)

  // --- region A: encoder phase ---
  u16* qkvb =(u16*)RA;                   // [16384,1536]
  u16* Sb16 =(u16*)(RA+12582912);        // [32,8,512,512]
  u16* ffb  =(u16*)(RA+46137344);        // [16384,2048]
  u16* ctxb =(u16*)(RA+62914560);        // [16384,512]
  u16* Vtb  =(u16*)(RA+67108864);        // [32*8*64,512]
  float* act0f=RA+71303168;
  float* act1f=RA+79691776;
  float* tmpf =RA+88080384;
  u16* act0b=(u16*)(RA+96468992);
  u16* act1b=(u16*)(RA+98566144);
  // --- region A: expert phase (aliases encoder bufs) ---
  u16* Pb   =(u16*)RA;                   // [101,4096,512] bf16
  float* abarf=RA+105906176;             // [3232,128] f32
  float* U  =RA+132382720;               // [4096,101]
  float* ctx1=RA+132796416;              // [3232,512]
  float* ctx2=RA+134451200;
  u16* ln1b =(u16*)(RA+136105984);       // [3232,512]
  u16* ln2b =(u16*)(RA+136933376);
  // --- region B: weights ---
  u16* posesb=(u16*)RB;                  // [16384,96]
  u16* W_inb =(u16*)(RB+786432);
  u16* eqwb  =(u16*)(RB+811008);
  u16* eowb  =(u16*)(RB+1597440);
  u16* ef1wb =(u16*)(RB+1859584);
  u16* ef2wb =(u16*)(RB+2908160);
  u16* wc1b  =(u16*)(RB+3956736);
  u16* wc2b  =(u16*)(RB+4349952);
  u16* mlpwb =(u16*)(RB+4743168);
  u16* hdwb  =(u16*)(RB+4874240);
  u16* xposb =(u16*)(RB+4899840);
  u16* owb   =(u16*)(RB+4925696);        // [101,512,512]
  u16* lwb   =(u16*)(RB+18163968);
  u16* wvb   =(u16*)(RB+31402240);       // [101,512,512]
  u16* wqkT  =(u16*)(RB+44640512);       // [202,512,512]  z=2e+half (q,k)
  u16* Gpb   =(u16*)(RB+71117056);       // [101,512,512]  G' = Wk^T Wq
  u16* Hb    =(u16*)(RB+84355328);       // [101,512]
  // --- region C ---
  u16* gmemb =(u16*)RC;                  // [4096,512]
  u16* p1b   =(u16*)(RC+1048576);        // [32,256,512]
  u16* membb =(u16*)(RC+3145728);        // [32,128,512]
  u16* wb    =(u16*)(RC+4194304);        // [101,32,512]
  u16* cmeanb=(u16*)(RC+5021696);        // [101,32,512]

  // ---- up-front converts ----
  cvt_pad<<<ceildiv(16384*96,256),256,0,stream>>>(poses,posesb,16384,86,96);
  cvt_pad<<<ceildiv(512*96,256),256,0,stream>>>(W_in,W_inb,512,86,96);
  cvt(stream,eq_w,eqwb,1572864);
  cvt(stream,eo_w,eowb,524288);
  cvt(stream,ef1_w,ef1wb,2097152);
  cvt(stream,ef2_w,ef2wb,2097152);
  cvt(stream,mlp_w,mlpwb,262144);
  cvt(stream,hd_w,hdwb,51200);
  cvt(stream,xp_pos,xposb,51712);
  cvt(stream,xp_o_w,owb,26476544);
  cvt(stream,xp_l_w,lwb,26476544);
  wrepackb<<<ceildiv(512*1536,256),256,0,stream>>>(c1_w,wc1b);
  wrepackb<<<ceildiv(512*1536,256),256,0,stream>>>(c2_w,wc2b);
  trcvtb<<<dim3(8,8,202),256,0,stream>>>(xp_qkv_w,wqkT);
  cvt_wv<<<ceildiv(101*32768,256),256,0,stream>>>(xp_qkv_w,wvb,(long long)101*32768);

  // ---- input projection + positional encoding (scalar epi3 path, R8) ----
  gemmB(stream, posesb,96,0,0, W_inb,96,0,0, b_in,0,0,
        act0f,act0b,512,0,0, 16384,512,96, 1,1, 3,1.f);

  // ---- 2 encoder layers (post-norm), attention batched z=256 ----
  for(int l=0;l<2;++l){
    gemmBig(stream, act0b,512,0,0, eqwb+(long long)l*786432,512,0,0,
          eq_b+(long long)l*1536,0,0, nullptr,qkvb,1536,0,0, 16384,1536,512, 1,1, 0,1.f);
    gemmB(stream, qkvb,1536,786432,64, qkvb+512,1536,786432,64, nullptr,0,0,
          nullptr,Sb16,512,2097152,262144, 512,512,64, 256,8, 0,0.125f);
    softmax512b<<<32768,256,0,stream>>>(Sb16,131072);
    vtransb<<<dim3(8,8,32),256,0,stream>>>(qkvb,Vtb);
    gemmB(stream, Sb16,512,2097152,262144, Vtb,512,262144,32768, nullptr,0,0,
          nullptr,ctxb,512,262144,64, 512,64,512, 256,8, 0,1.f);
    gemmBig(stream, ctxb,512,0,0, eowb+(long long)l*262144,512,0,0,
          eo_b+(long long)l*512,0,0, tmpf,nullptr,512,0,0, 16384,512,512, 1,1, 0,1.f);
    ln512<<<4096,256,0,stream>>>(tmpf,act0f,en1_g+(long long)l*512,en1_b+(long long)l*512,0,
                                 act1f,act1b,16384);
    gemmBig(stream, act1b,512,0,0, ef1wb+(long long)l*1048576,512,0,0,
          ef1_b+(long long)l*2048,0,0, nullptr,ffb,2048,0,0, 16384,2048,512, 1,1, 1,1.f);
    gemmBig(stream, ffb,2048,0,0, ef2wb+(long long)l*1048576,2048,0,0,
          ef2_b+(long long)l*512,0,0, tmpf,nullptr,512,0,0, 16384,512,2048, 1,1, 0,1.f);
    ln512<<<4096,256,0,stream>>>(tmpf,act1f,en2_g+(long long)l*512,en2_b+(long long)l*512,0,
                                 act0f,act0b,16384);
  }

  // ---- temporal pooling: conv-gelu-pool x2, then MLP-gelu ----
  u16* Ccb=(u16*)RA;   // aliases qkvb/Sb16 (encoder attn bufs dead)
  im2col3b<<<(int)(((long long)16384*1536/8+255)/256),256,0,stream>>>(act0b,Ccb,512,(long long)16384*1536/8);
  gemmBig(stream, Ccb,1536,0,0, wc1b,1536,0,0, c1_b,0,0,
        tmpf,nullptr,512,0,0, 16384,512,1536, 1,1, 2,1.f);
  pool2b<<<(int)(((long long)32*256*128+255)/256),256,0,stream>>>(tmpf,p1b,512,(long long)32*256*128);
  im2col3b<<<(int)(((long long)8192*1536/8+255)/256),256,0,stream>>>(p1b,Ccb,256,(long long)8192*1536/8);
  gemmBig(stream, Ccb,1536,0,0, wc2b,1536,0,0, c2_b,0,0,
        tmpf,nullptr,512,0,0, 8192,512,1536, 1,1, 2,1.f);
  pool2b<<<(int)(((long long)32*128*128+255)/256),256,0,stream>>>(tmpf,membb,256,(long long)32*128*128);
  gemmBig(stream, membb,512,0,0, mlpwb,512,0,0, mlp_b,0,0,
        nullptr,gmemb,512,0,0, 4096,512,512, 1,1, 2,1.f);

  // ---- experts (fused S+softmax+colmean) ----
  gemmBig(stream, wqkT+262144,512,524288,0, wqkT,512,524288,0, nullptr,0,0,
        nullptr,Gpb,512,262144,0, 512,512,512, 101,1, 0,1.f);
  gemmB(stream, Gpb,512,262144,0, xposb,512,512,0, nullptr,0,0,
        nullptr,Hb,1,512,0, 512,1,512, 101,1, 0,1.f);
  gemmB(stream, gmemb,512,0,0, Hb,512,0,0, nullptr,0,0,
        U,nullptr,101,0,0, 4096,101,512, 1,1, 0,ALPHA_S);
  gemmBig(stream, gmemb,512,0,0, Gpb,512,262144,0, nullptr,0,0,
        nullptr,Pb,512,2097152,0, 4096,512,512, 101,1, 0,1.f);
  gemm_sfused<<<3232,256,0,stream>>>(Pb, gmemb, U, abarf);
  expert_reduce2<<<dim3(32,101),256,0,stream>>>(abarf,gmemb,xp_pos,wb);
  gemmB(stream, wb,512,16384,0, wvb,512,262144,0, xp_qkv_b+1024,1536,0,
        nullptr,cmeanb,512,16384,0, 32,512,512, 101,1, 0,1.f);

  // ---- tail: proj -> LN -> proj -> LN(fn) -> head (permuted write) ----
  gemmB(stream, cmeanb,512,16384,0, owb,512,262144,0, xp_o_b,512,0,
        ctx1,nullptr,512,16384,0, 32,512,512, 101,1, 0,1.f);
  ln512<<<808,256,0,stream>>>(ctx1,nullptr,xp_n_g,xp_n_b,1, nullptr,ln1b,3232);
  gemmB(stream, ln1b,512,16384,0, lwb,512,262144,0, xp_l_b,512,0,
        ctx2,nullptr,512,16384,0, 32,512,512, 101,1, 0,1.f);
  ln512<<<808,256,0,stream>>>(ctx2,nullptr,fn_g,fn_b,0, nullptr,ln2b,3232);
  gemmB(stream, ln2b,512,0,0, hdwb,512,0,0, hd_b,0,0,
        out,nullptr,100,0,0, 3232,100,512, 1,1, 0,1.f, 1,1);
}

// Round 14
// 2058.637 us; speedup vs baseline: 1.0092x; 1.0092x over previous
//
#include <hip/hip_runtime.h>
#include <math.h>

typedef unsigned short u16;
typedef __bf16 bf16_t;
typedef bf16_t bf16x8 __attribute__((ext_vector_type(8)));
typedef float f32x4v __attribute__((ext_vector_type(4)));
typedef u16 u16x8 __attribute__((ext_vector_type(8)));
typedef u16 u16x4 __attribute__((ext_vector_type(4)));

__device__ inline u16 f2bf(float f){ __bf16 h=(__bf16)f; return __builtin_bit_cast(u16,h); }
__device__ inline float bf2f(u16 u){ unsigned int x=((unsigned int)u)<<16; return __builtin_bit_cast(float,x); }

#define GLD16(gp,lp) __builtin_amdgcn_global_load_lds( \
  (const __attribute__((address_space(1))) void*)(gp), \
  (__attribute__((address_space(3))) void*)(lp), 16, 0, 0)

#define MFMA_B16(a,b,c) __builtin_amdgcn_mfma_f32_16x16x32_bf16(a,b,c,0,0,0)
#define ALPHA_S 0.044194173824159216f

struct GP {
  const u16* A; int lda; long long sA1, sA2;
  const u16* B; int ldb; long long sB1, sB2;
  const float* bias; long long sb1, sb2, sbg;
  float* Cf; u16* Cb; int ldc; long long sC1, sC2;
  int M, N, K, Z2, epi, perm;
  float alpha;
};

__device__ inline float epiF(float v,int epi){
  if(epi==1) return fmaxf(v,0.f);
  if(epi==2) return 0.5f*v*(1.f+erff(v*0.70710678118654752f));
  return v;
}

// ---------------------------------------------------------------------------
// Small-tile kernel (128x128, 4 waves, BK=32, 3-buf depth-2 pipeline).
// Epilogue: R8-verified vectorized path (conflicts==0 measured). Don't touch.
// ---------------------------------------------------------------------------
__global__ __launch_bounds__(256) void gemm_bt(GP p){
  __shared__ u16 L[3*8192];
  const int z=blockIdx.z, z1=z/p.Z2, z2=z-z1*p.Z2;
  const u16* __restrict__ Ab = p.A + z1*p.sA1 + z2*p.sA2;
  const u16* __restrict__ Bb = p.B + z1*p.sB1 + z2*p.sB2;
  const int tm=blockIdx.x*128, tn=blockIdx.y*128;
  const int t=threadIdx.x, lane=t&63, wv=t>>6;
  const int wr=(wv>>1)*64, wc=(wv&1)*64;
  const int fr=lane&15, c16=lane>>4;

  long long aoff[2], boff[2];
  #pragma unroll
  for(int q=0;q<2;q++){
    int s=(wv*2+q)*64+lane;
    int r=s>>2;
    int col=((s&3)^((r>>1)&3))*8;
    int ga=tm+r; if(ga>p.M-1) ga=p.M-1;
    int gb=tn+r; if(gb>p.N-1) gb=p.N-1;
    aoff[q]=(long long)ga*p.lda+col;
    boff[q]=(long long)gb*p.ldb+col;
  }

  auto STAGE=[&](int tk,int buf){
    const long long kk=(long long)tk*32;
    u16* base=&L[buf*8192];
    #pragma unroll
    for(int q=0;q<2;q++){
      GLD16(Ab+aoff[q]+kk, base+(wv*2+q)*512);
      GLD16(Bb+boff[q]+kk, base+4096+(wv*2+q)*512);
    }
  };

  const int nt = p.K >> 5;
  f32x4v acc[4][4]={};

  STAGE(0,0);
  if(nt>1){
    STAGE(1,1);
    asm volatile("s_waitcnt vmcnt(4)" ::: "memory");
  } else {
    asm volatile("s_waitcnt vmcnt(0)" ::: "memory");
  }
  __builtin_amdgcn_s_barrier();
  __builtin_amdgcn_sched_barrier(0);

  for(int i=0;i<nt;++i){
    const int buf=i%3;
    if(i+2<nt) STAGE(i+2,(i+2)%3);
    const u16* Abuf=&L[buf*8192];
    const u16* Bbuf=&L[buf*8192+4096];
    bf16x8 af[4], bfv[4];
    #pragma unroll
    for(int m=0;m<4;m++){ int r=wr+16*m+fr; af[m]=*(const bf16x8*)&Abuf[r*32+((c16^((r>>1)&3))*8)]; }
    #pragma unroll
    for(int n=0;n<4;n++){ int r=wc+16*n+fr; bfv[n]=*(const bf16x8*)&Bbuf[r*32+((c16^((r>>1)&3))*8)]; }
    #pragma unroll
    for(int m=0;m<4;m++)
      #pragma unroll
      for(int n=0;n<4;n++)
        acc[m][n]=MFMA_B16(af[m],bfv[n],acc[m][n]);
    if(i+1<nt){
      if(i+2<nt) asm volatile("s_waitcnt vmcnt(4)" ::: "memory");
      else       asm volatile("s_waitcnt vmcnt(0)" ::: "memory");
      __builtin_amdgcn_s_barrier();
      __builtin_amdgcn_sched_barrier(0);
    }
  }

  const int rq=lane>>4;
  const long long cbase = z1*p.sC1 + z2*p.sC2;
  float* __restrict__ Cf = p.Cf? p.Cf+cbase : nullptr;
  u16*  __restrict__ Cbp = p.Cb? p.Cb+cbase : nullptr;

  const bool vec = (!p.perm) && (p.epi!=3) && ((p.N&63)==0) && !(Cf&&Cbp);
  if(vec){
    float bvn[4];
    #pragma unroll
    for(int n=0;n<4;n++){
      int gc=tn+wc+n*16+fr; if(gc>p.N-1) gc=p.N-1;
      bvn[n]=p.bias? p.bias[z1*p.sb1+z2*p.sb2+(long long)gc*p.sbg] : 0.f;
    }
    if(Cbp){
      u16* my=(u16*)L + wv*1024;
      #pragma unroll
      for(int m=0;m<4;m++){
        __syncthreads();
        #pragma unroll
        for(int n=0;n<4;n++){
          int pg=((n^rq)<<4)+fr;
          #pragma unroll
          for(int r=0;r<4;r++)
            my[(4*rq+r)*64+pg]=f2bf(epiF(acc[m][n][r]*p.alpha+bvn[n],p.epi));
        }
        __syncthreads();
        #pragma unroll
        for(int ps=0;ps<2;ps++){
          int row=ps*8+(lane>>3), h=lane&7;
          int grow=tm+wr+m*16+row, gc0=tn+wc+h*8;
          if(grow<p.M && gc0<p.N){
            int phys=(((h>>1)^(row>>2))<<4)+((h&1)<<3);
            *(u16x8*)&Cbp[(long long)grow*p.ldc+gc0]=*(const u16x8*)&my[row*64+phys];
          }
        }
      }
    } else {
      float* my=(float*)L + wv*1024;
      #pragma unroll
      for(int m=0;m<4;m++){
        __syncthreads();
        #pragma unroll
        for(int n=0;n<4;n++){
          int pg=((n^rq)<<4)+fr;
          #pragma unroll
          for(int r=0;r<4;r++)
            my[(4*rq+r)*64+pg]=epiF(acc[m][n][r]*p.alpha+bvn[n],p.epi);
        }
        __syncthreads();
        #pragma unroll
        for(int ps=0;ps<2;ps++){
          int row=ps*8+(lane>>3), h=lane&7;
          int grow=tm+wr+m*16+row, gc0=tn+wc+h*8;
          if(grow<p.M && gc0<p.N){
            int phys=(((h>>1)^(row>>2))<<4)+((h&1)<<3);
            *(float4*)&Cf[(long long)grow*p.ldc+gc0]  =*(const float4*)&my[row*64+phys];
            *(float4*)&Cf[(long long)grow*p.ldc+gc0+4]=*(const float4*)&my[row*64+phys+4];
          }
        }
      }
    }
    return;
  }

  #pragma unroll
  for(int m=0;m<4;m++){
    int grow0=tm+wr+16*m+4*rq;
    #pragma unroll
    for(int n=0;n<4;n++){
      int gcol=tn+wc+16*n+fr;
      if(gcol>=p.N) continue;
      float bv = p.bias? p.bias[z1*p.sb1+z2*p.sb2+(long long)gcol*p.sbg] : 0.f;
      #pragma unroll
      for(int r=0;r<4;r++){
        int grow=grow0+r;
        if(grow>=p.M) continue;
        float v=acc[m][n][r]*p.alpha+bv;
        if(p.epi==1) v=fmaxf(v,0.f);
        else if(p.epi==2) v=0.5f*v*(1.f+erff(v*0.70710678118654752f));
        else if(p.epi==3){
          int tt=grow&511;
          float ang=(float)tt*expf((float)(gcol&~1)*(-0.017988946039015967f));
          v += (gcol&1)? cosf(ang) : sinf(ang);
        }
        long long ci;
        if(p.perm) ci = ((long long)((grow&31)*101 + (grow>>5)))*100 + gcol;
        else       ci = (long long)grow*p.ldc+gcol;
        if(Cf) Cf[ci]=v;
        if(Cbp) Cbp[ci]=f2bf(v);
      }
    }
  }
}

// ---------------------------------------------------------------------------
// Fused expert-S kernel: one block per (e,b). K-loop identical to gemm_bt.
// Epilogue: S f32 -> LDS (pitch 132), float4 row softmax, column mean.
// ---------------------------------------------------------------------------
__global__ __launch_bounds__(256) void gemm_sfused(
    const u16* __restrict__ Pm, const u16* __restrict__ mem,
    const float* __restrict__ U, float* __restrict__ abar){
  __shared__ float Sl[128*132];           // 67.6 KB; low 48KB aliased as staging
  u16* L=(u16*)Sl;
  const int z=blockIdx.x, e=z>>5, b=z&31;
  const u16* __restrict__ Ab = Pm + (long long)e*2097152 + (long long)b*65536;
  const u16* __restrict__ Bb = mem + (long long)b*65536;
  const int t=threadIdx.x, lane=t&63, wv=t>>6;
  const int wr=(wv>>1)*64, wc=(wv&1)*64;
  const int fr=lane&15, c16=lane>>4;

  long long aoff[2], boff[2];
  #pragma unroll
  for(int q=0;q<2;q++){
    int s=(wv*2+q)*64+lane;
    int r=s>>2;
    int col=((s&3)^((r>>1)&3))*8;
    aoff[q]=(long long)r*512+col;
    boff[q]=(long long)r*512+col;
  }
  auto STAGE=[&](int tk,int buf){
    const long long kk=(long long)tk*32;
    u16* base=&L[buf*8192];
    #pragma unroll
    for(int q=0;q<2;q++){
      GLD16(Ab+aoff[q]+kk, base+(wv*2+q)*512);
      GLD16(Bb+boff[q]+kk, base+4096+(wv*2+q)*512);
    }
  };

  f32x4v acc[4][4]={};
  STAGE(0,0);
  STAGE(1,1);
  asm volatile("s_waitcnt vmcnt(4)" ::: "memory");
  __builtin_amdgcn_s_barrier();
  __builtin_amdgcn_sched_barrier(0);

  for(int i=0;i<16;++i){
    const int buf=i%3;
    if(i+2<16) STAGE(i+2,(i+2)%3);
    const u16* Abuf=&L[buf*8192];
    const u16* Bbuf=&L[buf*8192+4096];
    bf16x8 af[4], bfv[4];
    #pragma unroll
    for(int m=0;m<4;m++){ int r=wr+16*m+fr; af[m]=*(const bf16x8*)&Abuf[r*32+((c16^((r>>1)&3))*8)]; }
    #pragma unroll
    for(int n=0;n<4;n++){ int r=wc+16*n+fr; bfv[n]=*(const bf16x8*)&Bbuf[r*32+((c16^((r>>1)&3))*8)]; }
    #pragma unroll
    for(int m=0;m<4;m++)
      #pragma unroll
      for(int n=0;n<4;n++)
        acc[m][n]=MFMA_B16(af[m],bfv[n],acc[m][n]);
    if(i+1<16){
      if(i+2<16) asm volatile("s_waitcnt vmcnt(4)" ::: "memory");
      else       asm volatile("s_waitcnt vmcnt(0)" ::: "memory");
      __builtin_amdgcn_s_barrier();
      __builtin_amdgcn_sched_barrier(0);
    }
  }

  const int rq=lane>>4;
  float bvn[4];
  #pragma unroll
  for(int n=0;n<4;n++){
    int col=wc+n*16+fr;
    bvn[n]=U[((long long)(b*128+col))*101+e];
  }
  __syncthreads();                        // staging LDS reads done before alias
  #pragma unroll
  for(int m=0;m<4;m++)
    #pragma unroll
    for(int n=0;n<4;n++){
      int col=wc+n*16+fr;
      #pragma unroll
      for(int r=0;r<4;r++){
        int row=wr+m*16+4*rq+r;
        Sl[row*132+col]=acc[m][n][r]*ALPHA_S+bvn[n];
      }
    }
  __syncthreads();
  {
    int row=t>>1, h=t&1;
    float4* p4=(float4*)&Sl[row*132+h*64];
    float mx=-3.0e38f;
    #pragma unroll 4
    for(int j=0;j<16;j++){
      float4 v=p4[j];
      mx=fmaxf(mx,fmaxf(fmaxf(v.x,v.y),fmaxf(v.z,v.w)));
    }
    mx=fmaxf(mx,__shfl_xor(mx,1));
    float s=0.f;
    #pragma unroll 4
    for(int j=0;j<16;j++){
      float4 v=p4[j];
      v.x=__expf(v.x-mx); v.y=__expf(v.y-mx);
      v.z=__expf(v.z-mx); v.w=__expf(v.w-mx);
      s+=v.x+v.y+v.z+v.w;
      p4[j]=v;
    }
    s+=__shfl_xor(s,1);
    float inv=1.f/s;
    #pragma unroll 4
    for(int j=0;j<16;j++){
      float4 v=p4[j];
      v.x*=inv; v.y*=inv; v.z*=inv; v.w*=inv;
      p4[j]=v;
    }
  }
  __syncthreads();
  if(t<128){
    float s=0.f;
    for(int r=0;r<128;r++) s+=Sl[r*132+t];
    abar[(long long)z*128+t]=s*(1.f/128.f);
  }
}

// ---------------------------------------------------------------------------
// 8-phase big kernel: 256x256 tile, BK=64, 512 threads (8 waves 2Mx4N).
// K-loop + R8-verified epilogue (conflicts==0 measured). Don't touch.
// ---------------------------------------------------------------------------
__global__ __launch_bounds__(512) void gemm_big8(GP p){
  __shared__ u16 L[65536];   // 128 KB
  const int z=blockIdx.z, z1=z/p.Z2, z2=z-z1*p.Z2;
  const u16* __restrict__ Ab = p.A + z1*p.sA1 + z2*p.sA2;
  const u16* __restrict__ Bb = p.B + z1*p.sB1 + z2*p.sB2;
  const int tm=blockIdx.x*256, tn=blockIdx.y*256;
  const int t=threadIdx.x, lane=t&63, wv=t>>6;
  const int wr2=(wv>>2)*128, wc2=(wv&3)*64;
  const int fr=lane&15, c16=lane>>4;

  long long aoff[2], boff[2];
  {
    int rr=t>>2, cs=((t&3)^((t>>3)&3))*8;
    #pragma unroll
    for(int q=0;q<2;q++){
      int ga=tm+q*128+rr; if(ga>p.M-1) ga=p.M-1;
      int gb=tn+q*128+rr; if(gb>p.N-1) gb=p.N-1;
      aoff[q]=(long long)ga*p.lda+cs;
      boff[q]=(long long)gb*p.ldb+cs;
    }
  }

  auto STAGE_A=[&](int kt,int d,int ks){
    const long long k0=(long long)kt*64+ks*32;
    u16* dst=&L[d*16384+ks*8192];
    GLD16(Ab+aoff[0]+k0, dst+t*8);
    GLD16(Ab+aoff[1]+k0, dst+4096+t*8);
  };
  auto STAGE_B=[&](int kt,int d,int ks){
    const long long k0=(long long)kt*64+ks*32;
    u16* dst=&L[32768+d*16384+ks*8192];
    GLD16(Bb+boff[0]+k0, dst+t*8);
    GLD16(Bb+boff[1]+k0, dst+4096+t*8);
  };
  auto LDA_=[&](int d,int ks,int m)->bf16x8{
    int R=wr2+m*16+fr;
    return *(const bf16x8*)&L[d*16384+ks*8192+R*32+((c16^((R>>1)&3))*8)];
  };
  auto LDB_=[&](int d,int ks,int n)->bf16x8{
    int R=wc2+n*16+fr;
    return *(const bf16x8*)&L[32768+d*16384+ks*8192+R*32+((c16^((R>>1)&3))*8)];
  };

  const int ntk=p.K>>6;
  f32x4v acc[8][4]={};
  bf16x8 af[8], bq0, bq1, bq2, bq3;

  STAGE_A(0,0,0); STAGE_B(0,0,0); STAGE_A(0,0,1); STAGE_B(0,0,1);
  asm volatile("s_waitcnt vmcnt(4)" ::: "memory");
  __builtin_amdgcn_s_barrier();
  __builtin_amdgcn_sched_barrier(0);

  for(int kt=0;kt<ntk;++kt){
    const int d=kt&1, nd=d^1;
    const bool nxt=(kt+1<ntk);
    // phase 1
    #pragma unroll
    for(int m=0;m<8;m++) af[m]=LDA_(d,0,m);
    bq0=LDB_(d,0,0); bq1=LDB_(d,0,1);
    if(nxt) STAGE_A(kt+1,nd,0);
    __builtin_amdgcn_s_barrier();
    asm volatile("s_waitcnt lgkmcnt(0)" ::: "memory");
    __builtin_amdgcn_sched_barrier(0);
    __builtin_amdgcn_s_setprio(1);
    #pragma unroll
    for(int m=0;m<8;m++){
      acc[m][0]=MFMA_B16(af[m],bq0,acc[m][0]);
      acc[m][1]=MFMA_B16(af[m],bq1,acc[m][1]);
    }
    __builtin_amdgcn_s_setprio(0);
    __builtin_amdgcn_s_barrier();
    // phase 2
    bq2=LDB_(d,0,2); bq3=LDB_(d,0,3);
    if(nxt) STAGE_B(kt+1,nd,0);
    __builtin_amdgcn_s_barrier();
    asm volatile("s_waitcnt lgkmcnt(0)" ::: "memory");
    __builtin_amdgcn_sched_barrier(0);
    __builtin_amdgcn_s_setprio(1);
    #pragma unroll
    for(int m=0;m<8;m++){
      acc[m][2]=MFMA_B16(af[m],bq2,acc[m][2]);
      acc[m][3]=MFMA_B16(af[m],bq3,acc[m][3]);
    }
    __builtin_amdgcn_s_setprio(0);
    if(nxt) asm volatile("s_waitcnt vmcnt(4)" ::: "memory");
    else    asm volatile("s_waitcnt vmcnt(0)" ::: "memory");
    __builtin_amdgcn_s_barrier();
    __builtin_amdgcn_sched_barrier(0);
    // phase 3
    #pragma unroll
    for(int m=0;m<8;m++) af[m]=LDA_(d,1,m);
    bq0=LDB_(d,1,0); bq1=LDB_(d,1,1);
    if(nxt) STAGE_A(kt+1,nd,1);
    __builtin_amdgcn_s_barrier();
    asm volatile("s_waitcnt lgkmcnt(0)" ::: "memory");
    __builtin_amdgcn_sched_barrier(0);
    __builtin_amdgcn_s_setprio(1);
    #pragma unroll
    for(int m=0;m<8;m++){
      acc[m][0]=MFMA_B16(af[m],bq0,acc[m][0]);
      acc[m][1]=MFMA_B16(af[m],bq1,acc[m][1]);
    }
    __builtin_amdgcn_s_setprio(0);
    __builtin_amdgcn_s_barrier();
    // phase 4
    bq2=LDB_(d,1,2); bq3=LDB_(d,1,3);
    if(nxt) STAGE_B(kt+1,nd,1);
    __builtin_amdgcn_s_barrier();
    asm volatile("s_waitcnt lgkmcnt(0)" ::: "memory");
    __builtin_amdgcn_sched_barrier(0);
    __builtin_amdgcn_s_setprio(1);
    #pragma unroll
    for(int m=0;m<8;m++){
      acc[m][2]=MFMA_B16(af[m],bq2,acc[m][2]);
      acc[m][3]=MFMA_B16(af[m],bq3,acc[m][3]);
    }
    __builtin_amdgcn_s_setprio(0);
    if(nxt) asm volatile("s_waitcnt vmcnt(4)" ::: "memory");
    __builtin_amdgcn_s_barrier();
    __builtin_amdgcn_sched_barrier(0);
  }

  const int rq=lane>>4;
  const long long cbase = z1*p.sC1 + z2*p.sC2;
  float* __restrict__ Cf = p.Cf? p.Cf+cbase : nullptr;
  u16*  __restrict__ Cbp = p.Cb? p.Cb+cbase : nullptr;

  const bool vec = (!p.perm) && (p.epi!=3) && ((p.N&63)==0) && !(Cf&&Cbp);
  if(vec){
    float bvn[4];
    #pragma unroll
    for(int n=0;n<4;n++){
      int gc=tn+wc2+n*16+fr; if(gc>p.N-1) gc=p.N-1;
      bvn[n]=p.bias? p.bias[z1*p.sb1+z2*p.sb2+(long long)gc*p.sbg] : 0.f;
    }
    if(Cbp){
      u16* my=(u16*)L + wv*1024;
      #pragma unroll
      for(int m=0;m<8;m++){
        __syncthreads();
        #pragma unroll
        for(int n=0;n<4;n++){
          int pg=((n^rq)<<4)+fr;
          #pragma unroll
          for(int r=0;r<4;r++)
            my[(4*rq+r)*64+pg]=f2bf(epiF(acc[m][n][r]*p.alpha+bvn[n],p.epi));
        }
        __syncthreads();
        #pragma unroll
        for(int ps=0;ps<2;ps++){
          int row=ps*8+(lane>>3), h=lane&7;
          int grow=tm+wr2+m*16+row, gc0=tn+wc2+h*8;
          if(grow<p.M && gc0<p.N){
            int phys=(((h>>1)^(row>>2))<<4)+((h&1)<<3);
            *(u16x8*)&Cbp[(long long)grow*p.ldc+gc0]=*(const u16x8*)&my[row*64+phys];
          }
        }
      }
    } else {
      float* my=(float*)L + wv*1024;
      #pragma unroll
      for(int m=0;m<8;m++){
        __syncthreads();
        #pragma unroll
        for(int n=0;n<4;n++){
          int pg=((n^rq)<<4)+fr;
          #pragma unroll
          for(int r=0;r<4;r++)
            my[(4*rq+r)*64+pg]=epiF(acc[m][n][r]*p.alpha+bvn[n],p.epi);
        }
        __syncthreads();
        #pragma unroll
        for(int ps=0;ps<2;ps++){
          int row=ps*8+(lane>>3), h=lane&7;
          int grow=tm+wr2+m*16+row, gc0=tn+wc2+h*8;
          if(grow<p.M && gc0<p.N){
            int phys=(((h>>1)^(row>>2))<<4)+((h&1)<<3);
            *(float4*)&Cf[(long long)grow*p.ldc+gc0]  =*(const float4*)&my[row*64+phys];
            *(float4*)&Cf[(long long)grow*p.ldc+gc0+4]=*(const float4*)&my[row*64+phys+4];
          }
        }
      }
    }
    return;
  }

  #pragma unroll
  for(int m=0;m<8;m++){
    int grow0=tm+wr2+m*16+4*rq;
    #pragma unroll
    for(int n=0;n<4;n++){
      int gcol=tn+wc2+n*16+fr;
      if(gcol>=p.N) continue;
      float bv = p.bias? p.bias[z1*p.sb1+z2*p.sb2+gcol] : 0.f;
      #pragma unroll
      for(int r=0;r<4;r++){
        int grow=grow0+r;
        if(grow>=p.M) continue;
        float v=epiF(acc[m][n][r]*p.alpha+bv,p.epi);
        long long ci=(long long)grow*p.ldc+gcol;
        if(Cf) Cf[ci]=v;
        if(Cbp) Cbp[ci]=f2bf(v);
      }
    }
  }
}

// ---------------- row softmax over 512 cols, bf16 in-place -----------------
__global__ __launch_bounds__(256) void softmax512b(u16* __restrict__ S, int nrows){
  int row=blockIdx.x*4+(threadIdx.x>>6);
  if(row>=nrows) return;
  int lane=threadIdx.x&63;
  u16* p=S+(long long)row*512;
  u16x8 raw=*(u16x8*)&p[lane*8];
  float f[8];
  #pragma unroll
  for(int j=0;j<8;j++) f[j]=bf2f(raw[j]);
  float m=f[0];
  #pragma unroll
  for(int j=1;j<8;j++) m=fmaxf(m,f[j]);
  #pragma unroll
  for(int off=32;off;off>>=1) m=fmaxf(m,__shfl_xor(m,off));
  float s=0.f;
  #pragma unroll
  for(int j=0;j<8;j++){ f[j]=__expf(f[j]-m); s+=f[j]; }
  #pragma unroll
  for(int off=32;off;off>>=1) s+=__shfl_xor(s,off);
  float inv=1.f/s;
  u16x8 o;
  #pragma unroll
  for(int j=0;j<8;j++) o[j]=f2bf(f[j]*inv);
  *(u16x8*)&p[lane*8]=o;
}

// ------- LN rows of 512: y = LN(x [+res]) * g + b ; outputs f32/bf16 -------
__global__ __launch_bounds__(256) void ln512(
    const float* __restrict__ x, const float* __restrict__ res,
    const float* __restrict__ g, const float* __restrict__ bb, int pergroup,
    float* __restrict__ outf, u16* __restrict__ outb, int nrows)
{
  int row=blockIdx.x*4+(threadIdx.x>>6);
  if(row>=nrows) return;
  int lane=threadIdx.x&63;
  const float4* xp=(const float4*)(x+(long long)row*512);
  float4 v0=xp[lane], v1=xp[lane+64];
  if(res){
    const float4* rp=(const float4*)(res+(long long)row*512);
    float4 w0=rp[lane], w1=rp[lane+64];
    v0.x+=w0.x; v0.y+=w0.y; v0.z+=w0.z; v0.w+=w0.w;
    v1.x+=w1.x; v1.y+=w1.y; v1.z+=w1.z; v1.w+=w1.w;
  }
  float s=v0.x+v0.y+v0.z+v0.w+v1.x+v1.y+v1.z+v1.w;
  #pragma unroll
  for(int off=32;off;off>>=1) s+=__shfl_xor(s,off);
  float mu=s*(1.f/512.f);
  float q=(v0.x-mu)*(v0.x-mu)+(v0.y-mu)*(v0.y-mu)+(v0.z-mu)*(v0.z-mu)+(v0.w-mu)*(v0.w-mu)
        +(v1.x-mu)*(v1.x-mu)+(v1.y-mu)*(v1.y-mu)+(v1.z-mu)*(v1.z-mu)+(v1.w-mu)*(v1.w-mu);
  #pragma unroll
  for(int off=32;off;off>>=1) q+=__shfl_xor(q,off);
  float rstd=rsqrtf(q*(1.f/512.f)+1e-5f);
  long long go = pergroup? (long long)(row>>5)*512 : 0;
  float4 g0=((const float4*)(g+go))[lane],  g1=((const float4*)(g+go))[lane+64];
  float4 b0=((const float4*)(bb+go))[lane], b1=((const float4*)(bb+go))[lane+64];
  float4 o0,o1;
  o0.x=(v0.x-mu)*rstd*g0.x+b0.x; o0.y=(v0.y-mu)*rstd*g0.y+b0.y;
  o0.z=(v0.z-mu)*rstd*g0.z+b0.z; o0.w=(v0.w-mu)*rstd*g0.w+b0.w;
  o1.x=(v1.x-mu)*rstd*g1.x+b1.x; o1.y=(v1.y-mu)*rstd*g1.y+b1.y;
  o1.z=(v1.z-mu)*rstd*g1.z+b1.z; o1.w=(v1.w-mu)*rstd*g1.w+b1.w;
  if(outf){
    ((float4*)(outf+(long long)row*512))[lane]=o0;
    ((float4*)(outf+(long long)row*512))[lane+64]=o1;
  }
  if(outb){
    u16x4 h0,h1;
    h0[0]=f2bf(o0.x); h0[1]=f2bf(o0.y); h0[2]=f2bf(o0.z); h0[3]=f2bf(o0.w);
    h1[0]=f2bf(o1.x); h1[1]=f2bf(o1.y); h1[2]=f2bf(o1.z); h1[3]=f2bf(o1.w);
    ((u16x4*)(outb+(long long)row*512))[lane]=h0;
    ((u16x4*)(outb+(long long)row*512))[lane+64]=h1;
  }
}

// --------- transpose V slice of enc QKV (bf16), all 32 batches -------------
__global__ __launch_bounds__(256) void vtransb(const u16* __restrict__ qkv,
                                               u16* __restrict__ Vt){
  __shared__ u16 tile[64][72];
  int tt=blockIdx.x, h=blockIdx.y, zb=blockIdx.z;
  int t=threadIdx.x;
  int i=t>>2, j0=(t&3)*16;
  const u16* src = qkv + ((long long)(zb*512 + tt*64 + i))*1536 + 1024 + h*64 + j0;
  *(u16x8*)&tile[i][j0]   = *(const u16x8*)&src[0];
  *(u16x8*)&tile[i][j0+8] = *(const u16x8*)&src[8];
  __syncthreads();
  int j=t>>2, i0=(t&3)*16;
  u16 tmp[16];
  #pragma unroll
  for(int c=0;c<16;c++) tmp[c]=tile[i0+c][j];
  u16* dst = Vt + ((long long)((zb*8+h)*64 + j))*512 + tt*64 + i0;
  *(u16x8*)&dst[0]=*(u16x8*)&tmp[0];
  *(u16x8*)&dst[8]=*(u16x8*)&tmp[8];
}

// ------ transpose-convert [512,512] f32 tiles -> bf16 transposed -----------
__global__ __launch_bounds__(256) void trcvtb(const float* __restrict__ src,
                                              u16* __restrict__ dst){
  __shared__ float tile[64][65];
  int bi=blockIdx.x, bj=blockIdx.y, z=blockIdx.z;
  int e=z>>1, half=z&1;
  const float* s = src + (long long)e*786432 + half*262144;
  int t=threadIdx.x;
  int i=t>>2, j0=(t&3)*16;
  const float* sp = s + (long long)(bi*64+i)*512 + bj*64 + j0;
  #pragma unroll
  for(int c=0;c<4;c++){
    float4 v=((const float4*)sp)[c];
    tile[i][j0+4*c+0]=v.x; tile[i][j0+4*c+1]=v.y;
    tile[i][j0+4*c+2]=v.z; tile[i][j0+4*c+3]=v.w;
  }
  __syncthreads();
  int j=t>>2, i0=(t&3)*16;
  u16* d = dst + (long long)z*262144 + (long long)(bj*64+j)*512 + bi*64 + i0;
  u16x8 o0,o1;
  #pragma unroll
  for(int c=0;c<8;c++){ o0[c]=f2bf(tile[i0+c][j]); o1[c]=f2bf(tile[i0+8+c][j]); }
  *(u16x8*)&d[0]=o0; *(u16x8*)&d[8]=o1;
}

// ---------------- im2col for conv1d k=3 pad=1 (bf16 in/out) ----------------
__global__ __launch_bounds__(256) void im2col3b(const u16* __restrict__ in,
                                                u16* __restrict__ out,
                                                int Tlen, long long n8){
  long long idx=(long long)blockIdx.x*256+threadIdx.x;
  if(idx>=n8) return;
  int i8=(int)(idx&63); long long s=idx>>6;
  int dt=(int)(s%3); long long bt=s/3;
  int tt=(int)(bt%Tlen); int b=(int)(bt/Tlen);
  int tsrc=tt+dt-1;
  u16x8 v={0,0,0,0,0,0,0,0};
  if(tsrc>=0 && tsrc<Tlen) v=*(const u16x8*)&in[((long long)(b*Tlen+tsrc))*512 + i8*8];
  *(u16x8*)&out[idx*8]=v;
}

__global__ __launch_bounds__(256) void wrepackb(const float* __restrict__ w,
                                                u16* __restrict__ out){
  int idx=blockIdx.x*256+threadIdx.x;
  if(idx>=512*1536) return;
  int o=idx/1536; int rem=idx-o*1536;
  int dt=rem/512; int i=rem-dt*512;
  out[idx]=f2bf(w[((long long)o*512+i)*3+dt]);
}

// ------------- avgpool2 over time: f32 in -> bf16 out (4-wide) -------------
__global__ __launch_bounds__(256) void pool2b(const float* __restrict__ in,
                                              u16* __restrict__ out,
                                              int Tlen, long long n4){
  long long idx=(long long)blockIdx.x*256+threadIdx.x;
  if(idx>=n4) return;
  int c=(int)((idx&127)*4); long long s=idx>>7;
  int half=Tlen/2;
  int tp=(int)(s%half); int b=(int)(s/half);
  const float* p=in+((long long)(b*Tlen+2*tp))*512+c;
  float4 a=*(const float4*)p, d=*(const float4*)(p+512);
  u16x4 o;
  o[0]=f2bf(0.5f*(a.x+d.x)); o[1]=f2bf(0.5f*(a.y+d.y));
  o[2]=f2bf(0.5f*(a.z+d.z)); o[3]=f2bf(0.5f*(a.w+d.w));
  *(u16x4*)&out[(s*512)+c]=o;
}

// ---------------- flat f32 -> bf16 convert (8-wide) ------------------------
__global__ __launch_bounds__(256) void cvt_bf16(const float* __restrict__ in,
                                                u16* __restrict__ out, long long n8){
  long long i=(long long)blockIdx.x*256+threadIdx.x;
  if(i>=n8) return;
  const float4* p=(const float4*)(in+i*8);
  float4 a=p[0], b=p[1];
  u16x8 o;
  o[0]=f2bf(a.x); o[1]=f2bf(a.y); o[2]=f2bf(a.z); o[3]=f2bf(a.w);
  o[4]=f2bf(b.x); o[5]=f2bf(b.y); o[6]=f2bf(b.z); o[7]=f2bf(b.w);
  *(u16x8*)(out+i*8)=o;
}

// -------- strided chunk convert: 101 chunks of 262144 from stride 786432 ---
__global__ __launch_bounds__(256) void cvt_wv(const float* __restrict__ in,
                                              u16* __restrict__ out, long long n8){
  long long idx=(long long)blockIdx.x*256+threadIdx.x;
  if(idx>=n8) return;
  int e=(int)(idx>>15); long long r8=idx&32767;
  const float* p=in+(long long)e*786432+524288+r8*8;
  float4 a=((const float4*)p)[0], b=((const float4*)p)[1];
  u16x8 o;
  o[0]=f2bf(a.x); o[1]=f2bf(a.y); o[2]=f2bf(a.z); o[3]=f2bf(a.w);
  o[4]=f2bf(b.x); o[5]=f2bf(b.y); o[6]=f2bf(b.z); o[7]=f2bf(b.w);
  *(u16x8*)(out+idx*8)=o;
}

// -------- pad-convert rows: [rows,ks] f32 -> [rows,kd] bf16 (zero pad) -----
__global__ __launch_bounds__(256) void cvt_pad(const float* __restrict__ in,
                                               u16* __restrict__ out,
                                               int rows, int ks, int kd){
  long long idx=(long long)blockIdx.x*256+threadIdx.x;
  if(idx>=(long long)rows*kd) return;
  int r=(int)(idx/kd), c=(int)(idx-(long long)r*kd);
  out[idx]=(c<ks)? f2bf(in[(long long)r*ks+c]) : (u16)0;
}

// ---- per (b,e): w = abar@mem_b + pos_e (bf16) — softmax already fused -----
__global__ __launch_bounds__(256) void expert_reduce2(
    const float* __restrict__ abar, const u16* __restrict__ mem,
    const float* __restrict__ pos, u16* __restrict__ wout)
{
  int b=blockIdx.x, e=blockIdx.y;
  int t=threadIdx.x;
  __shared__ float abf[128];
  if(t<128) abf[t]=abar[((long long)(e*32+b))*128+t];
  __syncthreads();
  float c0=0.f, c1=0.f;
  const u16* mb = mem + (long long)b*65536;
  for(int k=0;k<128;++k){
    float a=abf[k];
    c0+=a*bf2f(mb[k*512+t]);
    c1+=a*bf2f(mb[k*512+t+256]);
  }
  c0+=pos[(long long)e*512+t]; c1+=pos[(long long)e*512+t+256];
  u16* o=wout+((long long)e*32+b)*512;
  o[t]=f2bf(c0); o[t+256]=f2bf(c1);
}

// ---------------------------------------------------------------------------
static inline int ceildiv(int a,int b){return (a+b-1)/b;}

static GP mkGP(const u16* A,int lda,long long sA1,long long sA2,
  const u16* B,int ldb,long long sB1,long long sB2,
  const float* bias,long long sb1,long long sb2,
  float* Cf,u16* Cb,int ldc,long long sC1,long long sC2,
  int M,int N,int K,int Z2,int epi,float alpha,long long sbg,int perm){
  GP p;
  p.A=A; p.lda=lda; p.sA1=sA1; p.sA2=sA2;
  p.B=B; p.ldb=ldb; p.sB1=sB1; p.sB2=sB2;
  p.bias=bias; p.sb1=sb1; p.sb2=sb2; p.sbg=sbg;
  p.Cf=Cf; p.Cb=Cb; p.ldc=ldc; p.sC1=sC1; p.sC2=sC2;
  p.M=M; p.N=N; p.K=K; p.Z2=Z2; p.epi=epi; p.perm=perm; p.alpha=alpha;
  return p;
}

static void gemmB(hipStream_t s,
  const u16* A,int lda,long long sA1,long long sA2,
  const u16* B,int ldb,long long sB1,long long sB2,
  const float* bias,long long sb1,long long sb2,
  float* Cf,u16* Cb,int ldc,long long sC1,long long sC2,
  int M,int N,int K,int Z,int Z2,int epi,float alpha,
  long long sbg=1,int perm=0){
  GP p=mkGP(A,lda,sA1,sA2,B,ldb,sB1,sB2,bias,sb1,sb2,Cf,Cb,ldc,sC1,sC2,M,N,K,Z2,epi,alpha,sbg,perm);
  dim3 g(ceildiv(M,128), ceildiv(N,128), Z);
  gemm_bt<<<g, dim3(256), 0, s>>>(p);
}

static void gemmBig(hipStream_t s,
  const u16* A,int lda,long long sA1,long long sA2,
  const u16* B,int ldb,long long sB1,long long sB2,
  const float* bias,long long sb1,long long sb2,
  float* Cf,u16* Cb,int ldc,long long sC1,long long sC2,
  int M,int N,int K,int Z,int Z2,int epi,float alpha){
  GP p=mkGP(A,lda,sA1,sA2,B,ldb,sB1,sB2,bias,sb1,sb2,Cf,Cb,ldc,sC1,sC2,M,N,K,Z2,epi,alpha,1,0);
  dim3 g(ceildiv(M,256), ceildiv(N,256), Z);
  gemm_big8<<<g, dim3(512), 0, s>>>(p);
}

static inline void cvt(hipStream_t s, const float* in, u16* out, long long n){
  long long n8=n/8;
  cvt_bf16<<<(int)((n8+255)/256),256,0,s>>>(in,out,n8);
}

extern "C" void kernel_launch(void* const* d_in, const int* in_sizes, int n_in,
                              void* d_out, int out_size, void* d_ws, size_t ws_size,
                              hipStream_t stream) {
  (void)in_sizes; (void)n_in; (void)out_size;
  const float* poses=(const float*)d_in[0];
  const float* W_in =(const float*)d_in[1];
  const float* b_in =(const float*)d_in[2];
  const float* eq_w =(const float*)d_in[3];
  const float* eq_b =(const float*)d_in[4];
  const float* eo_w =(const float*)d_in[5];
  const float* eo_b =(const float*)d_in[6];
  const float* ef1_w=(const float*)d_in[7];
  const float* ef1_b=(const float*)d_in[8];
  const float* ef2_w=(const float*)d_in[9];
  const float* ef2_b=(const float*)d_in[10];
  const float* en1_g=(const float*)d_in[11];
  const float* en1_b=(const float*)d_in[12];
  const float* en2_g=(const float*)d_in[13];
  const float* en2_b=(const float*)d_in[14];
  const float* c1_w =(const float*)d_in[15];
  const float* c1_b =(const float*)d_in[16];
  const float* c2_w =(const float*)d_in[17];
  const float* c2_b =(const float*)d_in[18];
  const float* mlp_w=(const float*)d_in[19];
  const float* mlp_b=(const float*)d_in[20];
  const float* xp_pos  =(const float*)d_in[21];
  const float* xp_qkv_w=(const float*)d_in[22];
  const float* xp_qkv_b=(const float*)d_in[23];
  const float* xp_o_w  =(const float*)d_in[24];
  const float* xp_o_b  =(const float*)d_in[25];
  const float* xp_n_g  =(const float*)d_in[26];
  const float* xp_n_b  =(const float*)d_in[27];
  const float* xp_l_w  =(const float*)d_in[28];
  const float* xp_l_b  =(const float*)d_in[29];
  const float* fn_g =(const float*)d_in[30];
  const float* fn_b =(const float*)d_in[31];
  const float* hd_w =(const float*)d_in[32];
  const float* hd_b =(const float*)d_in[33];
  float* out=(float*)d_out;

  float* ws=(float*)d_ws;
  size_t off=0;
  auto alloc=[&](size_t n)->float*{ float* p=ws+off; off+=(n+255)&~(size_t)255; return p; };
  float* RA = alloc(137760768);   // encoder-phase / expert-phase union
  float* RB = alloc(84381184);    // persistent converted weights
  float* RC = alloc(5849088);     // cross-phase (gmem, pools, w, cmean)
  if(off*sizeof(float) > ws_size) return;  // ws too small: bail (fails loudly)

  // --- region A: encoder phase ---
  u16* qkvb =(u16*)RA;                   // [16384,1536]
  u16* Sb16 =(u16*)(RA+12582912);        // [32,8,512,512]
  u16* ffb  =(u16*)(RA+46137344);        // [16384,2048]
  u16* ctxb =(u16*)(RA+62914560);        // [16384,512]
  u16* Vtb  =(u16*)(RA+67108864);        // [32*8*64,512]
  float* act0f=RA+71303168;
  float* act1f=RA+79691776;
  float* tmpf =RA+88080384;
  u16* act0b=(u16*)(RA+96468992);
  u16* act1b=(u16*)(RA+98566144);
  // --- region A: expert phase (aliases encoder bufs) ---
  u16* Pb   =(u16*)RA;                   // [101,4096,512] bf16
  float* abarf=RA+105906176;             // [3232,128] f32
  float* U  =RA+132382720;               // [4096,101]
  float* ctx1=RA+132796416;              // [3232,512]
  float* ctx2=RA+134451200;
  u16* ln1b =(u16*)(RA+136105984);       // [3232,512]
  u16* ln2b =(u16*)(RA+136933376);
  // --- region B: weights ---
  u16* posesb=(u16*)RB;                  // [16384,96]
  u16* W_inb =(u16*)(RB+786432);
  u16* eqwb  =(u16*)(RB+811008);
  u16* eowb  =(u16*)(RB+1597440);
  u16* ef1wb =(u16*)(RB+1859584);
  u16* ef2wb =(u16*)(RB+2908160);
  u16* wc1b  =(u16*)(RB+3956736);
  u16* wc2b  =(u16*)(RB+4349952);
  u16* mlpwb =(u16*)(RB+4743168);
  u16* hdwb  =(u16*)(RB+4874240);
  u16* xposb =(u16*)(RB+4899840);
  u16* owb   =(u16*)(RB+4925696);        // [101,512,512]
  u16* lwb   =(u16*)(RB+18163968);
  u16* wvb   =(u16*)(RB+31402240);       // [101,512,512]
  u16* wqkT  =(u16*)(RB+44640512);       // [202,512,512]  z=2e+half (q,k)
  u16* Gpb   =(u16*)(RB+71117056);       // [101,512,512]  G' = Wk^T Wq
  u16* Hb    =(u16*)(RB+84355328);       // [101,512]
  // --- region C ---
  u16* gmemb =(u16*)RC;                  // [4096,512]
  u16* p1b   =(u16*)(RC+1048576);        // [32,256,512]
  u16* membb =(u16*)(RC+3145728);        // [32,128,512]
  u16* wb    =(u16*)(RC+4194304);        // [101,32,512]
  u16* cmeanb=(u16*)(RC+5021696);        // [101,32,512]

  // ---- up-front converts ----
  cvt_pad<<<ceildiv(16384*96,256),256,0,stream>>>(poses,posesb,16384,86,96);
  cvt_pad<<<ceildiv(512*96,256),256,0,stream>>>(W_in,W_inb,512,86,96);
  cvt(stream,eq_w,eqwb,1572864);
  cvt(stream,eo_w,eowb,524288);
  cvt(stream,ef1_w,ef1wb,2097152);
  cvt(stream,ef2_w,ef2wb,2097152);
  cvt(stream,mlp_w,mlpwb,262144);
  cvt(stream,hd_w,hdwb,51200);
  cvt(stream,xp_pos,xposb,51712);
  cvt(stream,xp_o_w,owb,26476544);
  cvt(stream,xp_l_w,lwb,26476544);
  wrepackb<<<ceildiv(512*1536,256),256,0,stream>>>(c1_w,wc1b);
  wrepackb<<<ceildiv(512*1536,256),256,0,stream>>>(c2_w,wc2b);
  trcvtb<<<dim3(8,8,202),256,0,stream>>>(xp_qkv_w,wqkT);
  cvt_wv<<<ceildiv(101*32768,256),256,0,stream>>>(xp_qkv_w,wvb,(long long)101*32768);

  // ---- input projection + positional encoding (scalar epi3 path, R8) ----
  gemmB(stream, posesb,96,0,0, W_inb,96,0,0, b_in,0,0,
        act0f,act0b,512,0,0, 16384,512,96, 1,1, 3,1.f);

  // ---- 2 encoder layers (post-norm), attention batched z=256 ----
  for(int l=0;l<2;++l){
    gemmBig(stream, act0b,512,0,0, eqwb+(long long)l*786432,512,0,0,
          eq_b+(long long)l*1536,0,0, nullptr,qkvb,1536,0,0, 16384,1536,512, 1,1, 0,1.f);
    gemmB(stream, qkvb,1536,786432,64, qkvb+512,1536,786432,64, nullptr,0,0,
          nullptr,Sb16,512,2097152,262144, 512,512,64, 256,8, 0,0.125f);
    softmax512b<<<32768,256,0,stream>>>(Sb16,131072);
    vtransb<<<dim3(8,8,32),256,0,stream>>>(qkvb,Vtb);
    gemmB(stream, Sb16,512,2097152,262144, Vtb,512,262144,32768, nullptr,0,0,
          nullptr,ctxb,512,262144,64, 512,64,512, 256,8, 0,1.f);
    gemmBig(stream, ctxb,512,0,0, eowb+(long long)l*262144,512,0,0,
          eo_b+(long long)l*512,0,0, tmpf,nullptr,512,0,0, 16384,512,512, 1,1, 0,1.f);
    ln512<<<4096,256,0,stream>>>(tmpf,act0f,en1_g+(long long)l*512,en1_b+(long long)l*512,0,
                                 act1f,act1b,16384);
    gemmBig(stream, act1b,512,0,0, ef1wb+(long long)l*1048576,512,0,0,
          ef1_b+(long long)l*2048,0,0, nullptr,ffb,2048,0,0, 16384,2048,512, 1,1, 1,1.f);
    gemmBig(stream, ffb,2048,0,0, ef2wb+(long long)l*1048576,2048,0,0,
          ef2_b+(long long)l*512,0,0, tmpf,nullptr,512,0,0, 16384,512,2048, 1,1, 0,1.f);
    ln512<<<4096,256,0,stream>>>(tmpf,act1f,en2_g+(long long)l*512,en2_b+(long long)l*512,0,
                                 act0f,act0b,16384);
  }

  // ---- temporal pooling: conv-gelu-pool x2, then MLP-gelu ----
  u16* Ccb=(u16*)RA;   // aliases qkvb/Sb16 (encoder attn bufs dead)
  im2col3b<<<(int)(((long long)16384*1536/8+255)/256),256,0,stream>>>(act0b,Ccb,512,(long long)16384*1536/8);
  gemmBig(stream, Ccb,1536,0,0, wc1b,1536,0,0, c1_b,0,0,
        tmpf,nullptr,512,0,0, 16384,512,1536, 1,1, 2,1.f);
  pool2b<<<(int)(((long long)32*256*128+255)/256),256,0,stream>>>(tmpf,p1b,512,(long long)32*256*128);
  im2col3b<<<(int)(((long long)8192*1536/8+255)/256),256,0,stream>>>(p1b,Ccb,256,(long long)8192*1536/8);
  gemmBig(stream, Ccb,1536,0,0, wc2b,1536,0,0, c2_b,0,0,
        tmpf,nullptr,512,0,0, 8192,512,1536, 1,1, 2,1.f);
  pool2b<<<(int)(((long long)32*128*128+255)/256),256,0,stream>>>(tmpf,membb,256,(long long)32*128*128);
  gemmBig(stream, membb,512,0,0, mlpwb,512,0,0, mlp_b,0,0,
        nullptr,gmemb,512,0,0, 4096,512,512, 1,1, 2,1.f);

  // ---- experts (fused S+softmax+colmean) ----
  gemmBig(stream, wqkT+262144,512,524288,0, wqkT,512,524288,0, nullptr,0,0,
        nullptr,Gpb,512,262144,0, 512,512,512, 101,1, 0,1.f);
  gemmB(stream, Gpb,512,262144,0, xposb,512,512,0, nullptr,0,0,
        nullptr,Hb,1,512,0, 512,1,512, 101,1, 0,1.f);
  gemmB(stream, gmemb,512,0,0, Hb,512,0,0, nullptr,0,0,
        U,nullptr,101,0,0, 4096,101,512, 1,1, 0,ALPHA_S);
  gemmBig(stream, gmemb,512,0,0, Gpb,512,262144,0, nullptr,0,0,
        nullptr,Pb,512,2097152,0, 4096,512,512, 101,1, 0,1.f);
  gemm_sfused<<<3232,256,0,stream>>>(Pb, gmemb, U, abarf);
  expert_reduce2<<<dim3(32,101),256,0,stream>>>(abarf,gmemb,xp_pos,wb);
  gemmB(stream, wb,512,16384,0, wvb,512,262144,0, xp_qkv_b+1024,1536,0,
        nullptr,cmeanb,512,16384,0, 32,512,512, 101,1, 0,1.f);

  // ---- tail: proj -> LN -> proj -> LN(fn) -> head (permuted write) ----
  gemmB(stream, cmeanb,512,16384,0, owb,512,262144,0, xp_o_b,512,0,
        ctx1,nullptr,512,16384,0, 32,512,512, 101,1, 0,1.f);
  ln512<<<808,256,0,stream>>>(ctx1,nullptr,xp_n_g,xp_n_b,1, nullptr,ln1b,3232);
  gemmB(stream, ln1b,512,16384,0, lwb,512,262144,0, xp_l_b,512,0,
        ctx2,nullptr,512,16384,0, 32,512,512, 101,1, 0,1.f);
  ln512<<<808,256,0,stream>>>(ctx2,nullptr,fn_g,fn_b,0, nullptr,ln2b,3232);
  gemmB(stream, ln2b,512,0,0, hdwb,512,0,0, hd_b,0,0,
        out,nullptr,100,0,0, 3232,100,512, 1,1, 0,1.f, 1,1);
}

// Round 15
// 2026.018 us; speedup vs baseline: 1.0255x; 1.0161x over previous
//
#include <hip/hip_runtime.h>
#include <math.h>

typedef unsigned short u16;
typedef __bf16 bf16_t;
typedef bf16_t bf16x8 __attribute__((ext_vector_type(8)));
typedef float f32x4v __attribute__((ext_vector_type(4)));
typedef u16 u16x8 __attribute__((ext_vector_type(8)));
typedef u16 u16x4 __attribute__((ext_vector_type(4)));

__device__ inline u16 f2bf(float f){ __bf16 h=(__bf16)f; return __builtin_bit_cast(u16,h); }
__device__ inline float bf2f(u16 u){ unsigned int x=((unsigned int)u)<<16; return __builtin_bit_cast(float,x); }

#define GLD16(gp,lp) __builtin_amdgcn_global_load_lds( \
  (const __attribute__((address_space(1))) void*)(gp), \
  (__attribute__((address_space(3))) void*)(lp), 16, 0, 0)

#define MFMA_B16(a,b,c) __builtin_amdgcn_mfma_f32_16x16x32_bf16(a,b,c,0,0,0)
#define ALPHA_S 0.044194173824159216f

struct GP {
  const u16* A; int lda; long long sA1, sA2;
  const u16* B; int ldb; long long sB1, sB2;
  const float* bias; long long sb1, sb2, sbg;
  float* Cf; u16* Cb; int ldc; long long sC1, sC2;
  int M, N, K, Z2, epi, perm;
  float alpha;
};

__device__ inline float epiF(float v,int epi){
  if(epi==1) return fmaxf(v,0.f);
  if(epi==2) return 0.5f*v*(1.f+erff(v*0.70710678118654752f));
  return v;
}

// ---------------------------------------------------------------------------
// Small-tile kernel (128x128, 4 waves, BK=32, 3-buf depth-2 pipeline).
// Epilogue: R8-verified vectorized path (conflicts==0 measured). Don't touch.
// ---------------------------------------------------------------------------
__global__ __launch_bounds__(256) void gemm_bt(GP p){
  __shared__ u16 L[3*8192];
  const int z=blockIdx.z, z1=z/p.Z2, z2=z-z1*p.Z2;
  const u16* __restrict__ Ab = p.A + z1*p.sA1 + z2*p.sA2;
  const u16* __restrict__ Bb = p.B + z1*p.sB1 + z2*p.sB2;
  const int tm=blockIdx.x*128, tn=blockIdx.y*128;
  const int t=threadIdx.x, lane=t&63, wv=t>>6;
  const int wr=(wv>>1)*64, wc=(wv&1)*64;
  const int fr=lane&15, c16=lane>>4;

  long long aoff[2], boff[2];
  #pragma unroll
  for(int q=0;q<2;q++){
    int s=(wv*2+q)*64+lane;
    int r=s>>2;
    int col=((s&3)^((r>>1)&3))*8;
    int ga=tm+r; if(ga>p.M-1) ga=p.M-1;
    int gb=tn+r; if(gb>p.N-1) gb=p.N-1;
    aoff[q]=(long long)ga*p.lda+col;
    boff[q]=(long long)gb*p.ldb+col;
  }

  auto STAGE=[&](int tk,int buf){
    const long long kk=(long long)tk*32;
    u16* base=&L[buf*8192];
    #pragma unroll
    for(int q=0;q<2;q++){
      GLD16(Ab+aoff[q]+kk, base+(wv*2+q)*512);
      GLD16(Bb+boff[q]+kk, base+4096+(wv*2+q)*512);
    }
  };

  const int nt = p.K >> 5;
  f32x4v acc[4][4]={};

  STAGE(0,0);
  if(nt>1){
    STAGE(1,1);
    asm volatile("s_waitcnt vmcnt(4)" ::: "memory");
  } else {
    asm volatile("s_waitcnt vmcnt(0)" ::: "memory");
  }
  __builtin_amdgcn_s_barrier();
  __builtin_amdgcn_sched_barrier(0);

  for(int i=0;i<nt;++i){
    const int buf=i%3;
    if(i+2<nt) STAGE(i+2,(i+2)%3);
    const u16* Abuf=&L[buf*8192];
    const u16* Bbuf=&L[buf*8192+4096];
    bf16x8 af[4], bfv[4];
    #pragma unroll
    for(int m=0;m<4;m++){ int r=wr+16*m+fr; af[m]=*(const bf16x8*)&Abuf[r*32+((c16^((r>>1)&3))*8)]; }
    #pragma unroll
    for(int n=0;n<4;n++){ int r=wc+16*n+fr; bfv[n]=*(const bf16x8*)&Bbuf[r*32+((c16^((r>>1)&3))*8)]; }
    #pragma unroll
    for(int m=0;m<4;m++)
      #pragma unroll
      for(int n=0;n<4;n++)
        acc[m][n]=MFMA_B16(af[m],bfv[n],acc[m][n]);
    if(i+1<nt){
      if(i+2<nt) asm volatile("s_waitcnt vmcnt(4)" ::: "memory");
      else       asm volatile("s_waitcnt vmcnt(0)" ::: "memory");
      __builtin_amdgcn_s_barrier();
      __builtin_amdgcn_sched_barrier(0);
    }
  }

  const int rq=lane>>4;
  const long long cbase = z1*p.sC1 + z2*p.sC2;
  float* __restrict__ Cf = p.Cf? p.Cf+cbase : nullptr;
  u16*  __restrict__ Cbp = p.Cb? p.Cb+cbase : nullptr;

  const bool vec = (!p.perm) && (p.epi!=3) && ((p.N&63)==0) && !(Cf&&Cbp);
  if(vec){
    float bvn[4];
    #pragma unroll
    for(int n=0;n<4;n++){
      int gc=tn+wc+n*16+fr; if(gc>p.N-1) gc=p.N-1;
      bvn[n]=p.bias? p.bias[z1*p.sb1+z2*p.sb2+(long long)gc*p.sbg] : 0.f;
    }
    if(Cbp){
      u16* my=(u16*)L + wv*1024;
      #pragma unroll
      for(int m=0;m<4;m++){
        __syncthreads();
        #pragma unroll
        for(int n=0;n<4;n++){
          int pg=((n^rq)<<4)+fr;
          #pragma unroll
          for(int r=0;r<4;r++)
            my[(4*rq+r)*64+pg]=f2bf(epiF(acc[m][n][r]*p.alpha+bvn[n],p.epi));
        }
        __syncthreads();
        #pragma unroll
        for(int ps=0;ps<2;ps++){
          int row=ps*8+(lane>>3), h=lane&7;
          int grow=tm+wr+m*16+row, gc0=tn+wc+h*8;
          if(grow<p.M && gc0<p.N){
            int phys=(((h>>1)^(row>>2))<<4)+((h&1)<<3);
            *(u16x8*)&Cbp[(long long)grow*p.ldc+gc0]=*(const u16x8*)&my[row*64+phys];
          }
        }
      }
    } else {
      float* my=(float*)L + wv*1024;
      #pragma unroll
      for(int m=0;m<4;m++){
        __syncthreads();
        #pragma unroll
        for(int n=0;n<4;n++){
          int pg=((n^rq)<<4)+fr;
          #pragma unroll
          for(int r=0;r<4;r++)
            my[(4*rq+r)*64+pg]=epiF(acc[m][n][r]*p.alpha+bvn[n],p.epi);
        }
        __syncthreads();
        #pragma unroll
        for(int ps=0;ps<2;ps++){
          int row=ps*8+(lane>>3), h=lane&7;
          int grow=tm+wr+m*16+row, gc0=tn+wc+h*8;
          if(grow<p.M && gc0<p.N){
            int phys=(((h>>1)^(row>>2))<<4)+((h&1)<<3);
            *(float4*)&Cf[(long long)grow*p.ldc+gc0]  =*(const float4*)&my[row*64+phys];
            *(float4*)&Cf[(long long)grow*p.ldc+gc0+4]=*(const float4*)&my[row*64+phys+4];
          }
        }
      }
    }
    return;
  }

  #pragma unroll
  for(int m=0;m<4;m++){
    int grow0=tm+wr+16*m+4*rq;
    #pragma unroll
    for(int n=0;n<4;n++){
      int gcol=tn+wc+16*n+fr;
      if(gcol>=p.N) continue;
      float bv = p.bias? p.bias[z1*p.sb1+z2*p.sb2+(long long)gcol*p.sbg] : 0.f;
      #pragma unroll
      for(int r=0;r<4;r++){
        int grow=grow0+r;
        if(grow>=p.M) continue;
        float v=acc[m][n][r]*p.alpha+bv;
        if(p.epi==1) v=fmaxf(v,0.f);
        else if(p.epi==2) v=0.5f*v*(1.f+erff(v*0.70710678118654752f));
        else if(p.epi==3){
          int tt=grow&511;
          float ang=(float)tt*expf((float)(gcol&~1)*(-0.017988946039015967f));
          v += (gcol&1)? cosf(ang) : sinf(ang);
        }
        long long ci;
        if(p.perm) ci = ((long long)((grow&31)*101 + (grow>>5)))*100 + gcol;
        else       ci = (long long)grow*p.ldc+gcol;
        if(Cf) Cf[ci]=v;
        if(Cbp) Cbp[ci]=f2bf(v);
      }
    }
  }
}

// ---------------------------------------------------------------------------
// Fused expert-S kernel: one block per (e,b). K-loop identical to gemm_bt
// (M=N=128, K=512, lda=ldb=512). Epilogue: S f32 -> LDS (pad 129), row
// softmax (2 threads/row, shfl pair-reduce), column mean -> abar[z][128].
// Exact R12 configuration (best measured: 2030 us total).
// ---------------------------------------------------------------------------
__global__ __launch_bounds__(256) void gemm_sfused(
    const u16* __restrict__ Pm, const u16* __restrict__ mem,
    const float* __restrict__ U, float* __restrict__ abar){
  __shared__ float Sl[128*129];           // 66048 B; low 48KB aliased as staging
  u16* L=(u16*)Sl;
  const int z=blockIdx.x, e=z>>5, b=z&31;
  const u16* __restrict__ Ab = Pm + (long long)e*2097152 + (long long)b*65536;
  const u16* __restrict__ Bb = mem + (long long)b*65536;
  const int t=threadIdx.x, lane=t&63, wv=t>>6;
  const int wr=(wv>>1)*64, wc=(wv&1)*64;
  const int fr=lane&15, c16=lane>>4;

  long long aoff[2], boff[2];
  #pragma unroll
  for(int q=0;q<2;q++){
    int s=(wv*2+q)*64+lane;
    int r=s>>2;
    int col=((s&3)^((r>>1)&3))*8;
    aoff[q]=(long long)r*512+col;
    boff[q]=(long long)r*512+col;
  }
  auto STAGE=[&](int tk,int buf){
    const long long kk=(long long)tk*32;
    u16* base=&L[buf*8192];
    #pragma unroll
    for(int q=0;q<2;q++){
      GLD16(Ab+aoff[q]+kk, base+(wv*2+q)*512);
      GLD16(Bb+boff[q]+kk, base+4096+(wv*2+q)*512);
    }
  };

  f32x4v acc[4][4]={};
  STAGE(0,0);
  STAGE(1,1);
  asm volatile("s_waitcnt vmcnt(4)" ::: "memory");
  __builtin_amdgcn_s_barrier();
  __builtin_amdgcn_sched_barrier(0);

  for(int i=0;i<16;++i){
    const int buf=i%3;
    if(i+2<16) STAGE(i+2,(i+2)%3);
    const u16* Abuf=&L[buf*8192];
    const u16* Bbuf=&L[buf*8192+4096];
    bf16x8 af[4], bfv[4];
    #pragma unroll
    for(int m=0;m<4;m++){ int r=wr+16*m+fr; af[m]=*(const bf16x8*)&Abuf[r*32+((c16^((r>>1)&3))*8)]; }
    #pragma unroll
    for(int n=0;n<4;n++){ int r=wc+16*n+fr; bfv[n]=*(const bf16x8*)&Bbuf[r*32+((c16^((r>>1)&3))*8)]; }
    #pragma unroll
    for(int m=0;m<4;m++)
      #pragma unroll
      for(int n=0;n<4;n++)
        acc[m][n]=MFMA_B16(af[m],bfv[n],acc[m][n]);
    if(i+1<16){
      if(i+2<16) asm volatile("s_waitcnt vmcnt(4)" ::: "memory");
      else       asm volatile("s_waitcnt vmcnt(0)" ::: "memory");
      __builtin_amdgcn_s_barrier();
      __builtin_amdgcn_sched_barrier(0);
    }
  }

  const int rq=lane>>4;
  float bvn[4];
  #pragma unroll
  for(int n=0;n<4;n++){
    int col=wc+n*16+fr;
    bvn[n]=U[((long long)(b*128+col))*101+e];
  }
  __syncthreads();                        // staging LDS reads done before alias
  #pragma unroll
  for(int m=0;m<4;m++)
    #pragma unroll
    for(int n=0;n<4;n++){
      int col=wc+n*16+fr;
      #pragma unroll
      for(int r=0;r<4;r++){
        int row=wr+m*16+4*rq+r;
        Sl[row*129+col]=acc[m][n][r]*ALPHA_S+bvn[n];
      }
    }
  __syncthreads();
  {
    int row=t>>1, h=t&1;
    float* pr=&Sl[row*129+h*64];
    float mx=pr[0];
    for(int j=1;j<64;j++) mx=fmaxf(mx,pr[j]);
    mx=fmaxf(mx,__shfl_xor(mx,1));
    float s=0.f;
    for(int j=0;j<64;j++){ float ex=__expf(pr[j]-mx); pr[j]=ex; s+=ex; }
    s+=__shfl_xor(s,1);
    float inv=1.f/s;
    for(int j=0;j<64;j++) pr[j]*=inv;
  }
  __syncthreads();
  if(t<128){
    float s=0.f;
    for(int r=0;r<128;r++) s+=Sl[r*129+t];
    abar[(long long)z*128+t]=s*(1.f/128.f);
  }
}

// ---------------------------------------------------------------------------
// 8-phase big kernel: 256x256 tile, BK=64, 512 threads (8 waves 2Mx4N).
// K-loop + R8-verified epilogue (conflicts==0 measured). Don't touch.
// ---------------------------------------------------------------------------
__global__ __launch_bounds__(512) void gemm_big8(GP p){
  __shared__ u16 L[65536];   // 128 KB
  const int z=blockIdx.z, z1=z/p.Z2, z2=z-z1*p.Z2;
  const u16* __restrict__ Ab = p.A + z1*p.sA1 + z2*p.sA2;
  const u16* __restrict__ Bb = p.B + z1*p.sB1 + z2*p.sB2;
  const int tm=blockIdx.x*256, tn=blockIdx.y*256;
  const int t=threadIdx.x, lane=t&63, wv=t>>6;
  const int wr2=(wv>>2)*128, wc2=(wv&3)*64;
  const int fr=lane&15, c16=lane>>4;

  long long aoff[2], boff[2];
  {
    int rr=t>>2, cs=((t&3)^((t>>3)&3))*8;
    #pragma unroll
    for(int q=0;q<2;q++){
      int ga=tm+q*128+rr; if(ga>p.M-1) ga=p.M-1;
      int gb=tn+q*128+rr; if(gb>p.N-1) gb=p.N-1;
      aoff[q]=(long long)ga*p.lda+cs;
      boff[q]=(long long)gb*p.ldb+cs;
    }
  }

  auto STAGE_A=[&](int kt,int d,int ks){
    const long long k0=(long long)kt*64+ks*32;
    u16* dst=&L[d*16384+ks*8192];
    GLD16(Ab+aoff[0]+k0, dst+t*8);
    GLD16(Ab+aoff[1]+k0, dst+4096+t*8);
  };
  auto STAGE_B=[&](int kt,int d,int ks){
    const long long k0=(long long)kt*64+ks*32;
    u16* dst=&L[32768+d*16384+ks*8192];
    GLD16(Bb+boff[0]+k0, dst+t*8);
    GLD16(Bb+boff[1]+k0, dst+4096+t*8);
  };
  auto LDA_=[&](int d,int ks,int m)->bf16x8{
    int R=wr2+m*16+fr;
    return *(const bf16x8*)&L[d*16384+ks*8192+R*32+((c16^((R>>1)&3))*8)];
  };
  auto LDB_=[&](int d,int ks,int n)->bf16x8{
    int R=wc2+n*16+fr;
    return *(const bf16x8*)&L[32768+d*16384+ks*8192+R*32+((c16^((R>>1)&3))*8)];
  };

  const int ntk=p.K>>6;
  f32x4v acc[8][4]={};
  bf16x8 af[8], bq0, bq1, bq2, bq3;

  STAGE_A(0,0,0); STAGE_B(0,0,0); STAGE_A(0,0,1); STAGE_B(0,0,1);
  asm volatile("s_waitcnt vmcnt(4)" ::: "memory");
  __builtin_amdgcn_s_barrier();
  __builtin_amdgcn_sched_barrier(0);

  for(int kt=0;kt<ntk;++kt){
    const int d=kt&1, nd=d^1;
    const bool nxt=(kt+1<ntk);
    // phase 1
    #pragma unroll
    for(int m=0;m<8;m++) af[m]=LDA_(d,0,m);
    bq0=LDB_(d,0,0); bq1=LDB_(d,0,1);
    if(nxt) STAGE_A(kt+1,nd,0);
    __builtin_amdgcn_s_barrier();
    asm volatile("s_waitcnt lgkmcnt(0)" ::: "memory");
    __builtin_amdgcn_sched_barrier(0);
    __builtin_amdgcn_s_setprio(1);
    #pragma unroll
    for(int m=0;m<8;m++){
      acc[m][0]=MFMA_B16(af[m],bq0,acc[m][0]);
      acc[m][1]=MFMA_B16(af[m],bq1,acc[m][1]);
    }
    __builtin_amdgcn_s_setprio(0);
    __builtin_amdgcn_s_barrier();
    // phase 2
    bq2=LDB_(d,0,2); bq3=LDB_(d,0,3);
    if(nxt) STAGE_B(kt+1,nd,0);
    __builtin_amdgcn_s_barrier();
    asm volatile("s_waitcnt lgkmcnt(0)" ::: "memory");
    __builtin_amdgcn_sched_barrier(0);
    __builtin_amdgcn_s_setprio(1);
    #pragma unroll
    for(int m=0;m<8;m++){
      acc[m][2]=MFMA_B16(af[m],bq2,acc[m][2]);
      acc[m][3]=MFMA_B16(af[m],bq3,acc[m][3]);
    }
    __builtin_amdgcn_s_setprio(0);
    if(nxt) asm volatile("s_waitcnt vmcnt(4)" ::: "memory");
    else    asm volatile("s_waitcnt vmcnt(0)" ::: "memory");
    __builtin_amdgcn_s_barrier();
    __builtin_amdgcn_sched_barrier(0);
    // phase 3
    #pragma unroll
    for(int m=0;m<8;m++) af[m]=LDA_(d,1,m);
    bq0=LDB_(d,1,0); bq1=LDB_(d,1,1);
    if(nxt) STAGE_A(kt+1,nd,1);
    __builtin_amdgcn_s_barrier();
    asm volatile("s_waitcnt lgkmcnt(0)" ::: "memory");
    __builtin_amdgcn_sched_barrier(0);
    __builtin_amdgcn_s_setprio(1);
    #pragma unroll
    for(int m=0;m<8;m++){
      acc[m][0]=MFMA_B16(af[m],bq0,acc[m][0]);
      acc[m][1]=MFMA_B16(af[m],bq1,acc[m][1]);
    }
    __builtin_amdgcn_s_setprio(0);
    __builtin_amdgcn_s_barrier();
    // phase 4
    bq2=LDB_(d,1,2); bq3=LDB_(d,1,3);
    if(nxt) STAGE_B(kt+1,nd,1);
    __builtin_amdgcn_s_barrier();
    asm volatile("s_waitcnt lgkmcnt(0)" ::: "memory");
    __builtin_amdgcn_sched_barrier(0);
    __builtin_amdgcn_s_setprio(1);
    #pragma unroll
    for(int m=0;m<8;m++){
      acc[m][2]=MFMA_B16(af[m],bq2,acc[m][2]);
      acc[m][3]=MFMA_B16(af[m],bq3,acc[m][3]);
    }
    __builtin_amdgcn_s_setprio(0);
    if(nxt) asm volatile("s_waitcnt vmcnt(4)" ::: "memory");
    __builtin_amdgcn_s_barrier();
    __builtin_amdgcn_sched_barrier(0);
  }

  const int rq=lane>>4;
  const long long cbase = z1*p.sC1 + z2*p.sC2;
  float* __restrict__ Cf = p.Cf? p.Cf+cbase : nullptr;
  u16*  __restrict__ Cbp = p.Cb? p.Cb+cbase : nullptr;

  const bool vec = (!p.perm) && (p.epi!=3) && ((p.N&63)==0) && !(Cf&&Cbp);
  if(vec){
    float bvn[4];
    #pragma unroll
    for(int n=0;n<4;n++){
      int gc=tn+wc2+n*16+fr; if(gc>p.N-1) gc=p.N-1;
      bvn[n]=p.bias? p.bias[z1*p.sb1+z2*p.sb2+(long long)gc*p.sbg] : 0.f;
    }
    if(Cbp){
      u16* my=(u16*)L + wv*1024;
      #pragma unroll
      for(int m=0;m<8;m++){
        __syncthreads();
        #pragma unroll
        for(int n=0;n<4;n++){
          int pg=((n^rq)<<4)+fr;
          #pragma unroll
          for(int r=0;r<4;r++)
            my[(4*rq+r)*64+pg]=f2bf(epiF(acc[m][n][r]*p.alpha+bvn[n],p.epi));
        }
        __syncthreads();
        #pragma unroll
        for(int ps=0;ps<2;ps++){
          int row=ps*8+(lane>>3), h=lane&7;
          int grow=tm+wr2+m*16+row, gc0=tn+wc2+h*8;
          if(grow<p.M && gc0<p.N){
            int phys=(((h>>1)^(row>>2))<<4)+((h&1)<<3);
            *(u16x8*)&Cbp[(long long)grow*p.ldc+gc0]=*(const u16x8*)&my[row*64+phys];
          }
        }
      }
    } else {
      float* my=(float*)L + wv*1024;
      #pragma unroll
      for(int m=0;m<8;m++){
        __syncthreads();
        #pragma unroll
        for(int n=0;n<4;n++){
          int pg=((n^rq)<<4)+fr;
          #pragma unroll
          for(int r=0;r<4;r++)
            my[(4*rq+r)*64+pg]=epiF(acc[m][n][r]*p.alpha+bvn[n],p.epi);
        }
        __syncthreads();
        #pragma unroll
        for(int ps=0;ps<2;ps++){
          int row=ps*8+(lane>>3), h=lane&7;
          int grow=tm+wr2+m*16+row, gc0=tn+wc2+h*8;
          if(grow<p.M && gc0<p.N){
            int phys=(((h>>1)^(row>>2))<<4)+((h&1)<<3);
            *(float4*)&Cf[(long long)grow*p.ldc+gc0]  =*(const float4*)&my[row*64+phys];
            *(float4*)&Cf[(long long)grow*p.ldc+gc0+4]=*(const float4*)&my[row*64+phys+4];
          }
        }
      }
    }
    return;
  }

  #pragma unroll
  for(int m=0;m<8;m++){
    int grow0=tm+wr2+m*16+4*rq;
    #pragma unroll
    for(int n=0;n<4;n++){
      int gcol=tn+wc2+n*16+fr;
      if(gcol>=p.N) continue;
      float bv = p.bias? p.bias[z1*p.sb1+z2*p.sb2+gcol] : 0.f;
      #pragma unroll
      for(int r=0;r<4;r++){
        int grow=grow0+r;
        if(grow>=p.M) continue;
        float v=epiF(acc[m][n][r]*p.alpha+bv,p.epi);
        long long ci=(long long)grow*p.ldc+gcol;
        if(Cf) Cf[ci]=v;
        if(Cbp) Cbp[ci]=f2bf(v);
      }
    }
  }
}

// ---------------- row softmax over 512 cols, bf16 in-place -----------------
__global__ __launch_bounds__(256) void softmax512b(u16* __restrict__ S, int nrows){
  int row=blockIdx.x*4+(threadIdx.x>>6);
  if(row>=nrows) return;
  int lane=threadIdx.x&63;
  u16* p=S+(long long)row*512;
  u16x8 raw=*(u16x8*)&p[lane*8];
  float f[8];
  #pragma unroll
  for(int j=0;j<8;j++) f[j]=bf2f(raw[j]);
  float m=f[0];
  #pragma unroll
  for(int j=1;j<8;j++) m=fmaxf(m,f[j]);
  #pragma unroll
  for(int off=32;off;off>>=1) m=fmaxf(m,__shfl_xor(m,off));
  float s=0.f;
  #pragma unroll
  for(int j=0;j<8;j++){ f[j]=__expf(f[j]-m); s+=f[j]; }
  #pragma unroll
  for(int off=32;off;off>>=1) s+=__shfl_xor(s,off);
  float inv=1.f/s;
  u16x8 o;
  #pragma unroll
  for(int j=0;j<8;j++) o[j]=f2bf(f[j]*inv);
  *(u16x8*)&p[lane*8]=o;
}

// ------- LN rows of 512: y = LN(x [+res]) * g + b ; outputs f32/bf16 -------
__global__ __launch_bounds__(256) void ln512(
    const float* __restrict__ x, const float* __restrict__ res,
    const float* __restrict__ g, const float* __restrict__ bb, int pergroup,
    float* __restrict__ outf, u16* __restrict__ outb, int nrows)
{
  int row=blockIdx.x*4+(threadIdx.x>>6);
  if(row>=nrows) return;
  int lane=threadIdx.x&63;
  const float4* xp=(const float4*)(x+(long long)row*512);
  float4 v0=xp[lane], v1=xp[lane+64];
  if(res){
    const float4* rp=(const float4*)(res+(long long)row*512);
    float4 w0=rp[lane], w1=rp[lane+64];
    v0.x+=w0.x; v0.y+=w0.y; v0.z+=w0.z; v0.w+=w0.w;
    v1.x+=w1.x; v1.y+=w1.y; v1.z+=w1.z; v1.w+=w1.w;
  }
  float s=v0.x+v0.y+v0.z+v0.w+v1.x+v1.y+v1.z+v1.w;
  #pragma unroll
  for(int off=32;off;off>>=1) s+=__shfl_xor(s,off);
  float mu=s*(1.f/512.f);
  float q=(v0.x-mu)*(v0.x-mu)+(v0.y-mu)*(v0.y-mu)+(v0.z-mu)*(v0.z-mu)+(v0.w-mu)*(v0.w-mu)
        +(v1.x-mu)*(v1.x-mu)+(v1.y-mu)*(v1.y-mu)+(v1.z-mu)*(v1.z-mu)+(v1.w-mu)*(v1.w-mu);
  #pragma unroll
  for(int off=32;off;off>>=1) q+=__shfl_xor(q,off);
  float rstd=rsqrtf(q*(1.f/512.f)+1e-5f);
  long long go = pergroup? (long long)(row>>5)*512 : 0;
  float4 g0=((const float4*)(g+go))[lane],  g1=((const float4*)(g+go))[lane+64];
  float4 b0=((const float4*)(bb+go))[lane], b1=((const float4*)(bb+go))[lane+64];
  float4 o0,o1;
  o0.x=(v0.x-mu)*rstd*g0.x+b0.x; o0.y=(v0.y-mu)*rstd*g0.y+b0.y;
  o0.z=(v0.z-mu)*rstd*g0.z+b0.z; o0.w=(v0.w-mu)*rstd*g0.w+b0.w;
  o1.x=(v1.x-mu)*rstd*g1.x+b1.x; o1.y=(v1.y-mu)*rstd*g1.y+b1.y;
  o1.z=(v1.z-mu)*rstd*g1.z+b1.z; o1.w=(v1.w-mu)*rstd*g1.w+b1.w;
  if(outf){
    ((float4*)(outf+(long long)row*512))[lane]=o0;
    ((float4*)(outf+(long long)row*512))[lane+64]=o1;
  }
  if(outb){
    u16x4 h0,h1;
    h0[0]=f2bf(o0.x); h0[1]=f2bf(o0.y); h0[2]=f2bf(o0.z); h0[3]=f2bf(o0.w);
    h1[0]=f2bf(o1.x); h1[1]=f2bf(o1.y); h1[2]=f2bf(o1.z); h1[3]=f2bf(o1.w);
    ((u16x4*)(outb+(long long)row*512))[lane]=h0;
    ((u16x4*)(outb+(long long)row*512))[lane+64]=h1;
  }
}

// --------- transpose V slice of enc QKV (bf16), all 32 batches -------------
__global__ __launch_bounds__(256) void vtransb(const u16* __restrict__ qkv,
                                               u16* __restrict__ Vt){
  __shared__ u16 tile[64][72];
  int tt=blockIdx.x, h=blockIdx.y, zb=blockIdx.z;
  int t=threadIdx.x;
  int i=t>>2, j0=(t&3)*16;
  const u16* src = qkv + ((long long)(zb*512 + tt*64 + i))*1536 + 1024 + h*64 + j0;
  *(u16x8*)&tile[i][j0]   = *(const u16x8*)&src[0];
  *(u16x8*)&tile[i][j0+8] = *(const u16x8*)&src[8];
  __syncthreads();
  int j=t>>2, i0=(t&3)*16;
  u16 tmp[16];
  #pragma unroll
  for(int c=0;c<16;c++) tmp[c]=tile[i0+c][j];
  u16* dst = Vt + ((long long)((zb*8+h)*64 + j))*512 + tt*64 + i0;
  *(u16x8*)&dst[0]=*(u16x8*)&tmp[0];
  *(u16x8*)&dst[8]=*(u16x8*)&tmp[8];
}

// ------ transpose-convert [512,512] f32 tiles -> bf16 transposed -----------
__global__ __launch_bounds__(256) void trcvtb(const float* __restrict__ src,
                                              u16* __restrict__ dst){
  __shared__ float tile[64][65];
  int bi=blockIdx.x, bj=blockIdx.y, z=blockIdx.z;
  int e=z>>1, half=z&1;
  const float* s = src + (long long)e*786432 + half*262144;
  int t=threadIdx.x;
  int i=t>>2, j0=(t&3)*16;
  const float* sp = s + (long long)(bi*64+i)*512 + bj*64 + j0;
  #pragma unroll
  for(int c=0;c<4;c++){
    float4 v=((const float4*)sp)[c];
    tile[i][j0+4*c+0]=v.x; tile[i][j0+4*c+1]=v.y;
    tile[i][j0+4*c+2]=v.z; tile[i][j0+4*c+3]=v.w;
  }
  __syncthreads();
  int j=t>>2, i0=(t&3)*16;
  u16* d = dst + (long long)z*262144 + (long long)(bj*64+j)*512 + bi*64 + i0;
  u16x8 o0,o1;
  #pragma unroll
  for(int c=0;c<8;c++){ o0[c]=f2bf(tile[i0+c][j]); o1[c]=f2bf(tile[i0+8+c][j]); }
  *(u16x8*)&d[0]=o0; *(u16x8*)&d[8]=o1;
}

// ---------------- im2col for conv1d k=3 pad=1 (bf16 in/out) ----------------
__global__ __launch_bounds__(256) void im2col3b(const u16* __restrict__ in,
                                                u16* __restrict__ out,
                                                int Tlen, long long n8){
  long long idx=(long long)blockIdx.x*256+threadIdx.x;
  if(idx>=n8) return;
  int i8=(int)(idx&63); long long s=idx>>6;
  int dt=(int)(s%3); long long bt=s/3;
  int tt=(int)(bt%Tlen); int b=(int)(bt/Tlen);
  int tsrc=tt+dt-1;
  u16x8 v={0,0,0,0,0,0,0,0};
  if(tsrc>=0 && tsrc<Tlen) v=*(const u16x8*)&in[((long long)(b*Tlen+tsrc))*512 + i8*8];
  *(u16x8*)&out[idx*8]=v;
}

__global__ __launch_bounds__(256) void wrepackb(const float* __restrict__ w,
                                                u16* __restrict__ out){
  int idx=blockIdx.x*256+threadIdx.x;
  if(idx>=512*1536) return;
  int o=idx/1536; int rem=idx-o*1536;
  int dt=rem/512; int i=rem-dt*512;
  out[idx]=f2bf(w[((long long)o*512+i)*3+dt]);
}

// ------------- avgpool2 over time: f32 in -> bf16 out (4-wide) -------------
__global__ __launch_bounds__(256) void pool2b(const float* __restrict__ in,
                                              u16* __restrict__ out,
                                              int Tlen, long long n4){
  long long idx=(long long)blockIdx.x*256+threadIdx.x;
  if(idx>=n4) return;
  int c=(int)((idx&127)*4); long long s=idx>>7;
  int half=Tlen/2;
  int tp=(int)(s%half); int b=(int)(s/half);
  const float* p=in+((long long)(b*Tlen+2*tp))*512+c;
  float4 a=*(const float4*)p, d=*(const float4*)(p+512);
  u16x4 o;
  o[0]=f2bf(0.5f*(a.x+d.x)); o[1]=f2bf(0.5f*(a.y+d.y));
  o[2]=f2bf(0.5f*(a.z+d.z)); o[3]=f2bf(0.5f*(a.w+d.w));
  *(u16x4*)&out[(s*512)+c]=o;
}

// ---------------- flat f32 -> bf16 convert (8-wide) ------------------------
__global__ __launch_bounds__(256) void cvt_bf16(const float* __restrict__ in,
                                                u16* __restrict__ out, long long n8){
  long long i=(long long)blockIdx.x*256+threadIdx.x;
  if(i>=n8) return;
  const float4* p=(const float4*)(in+i*8);
  float4 a=p[0], b=p[1];
  u16x8 o;
  o[0]=f2bf(a.x); o[1]=f2bf(a.y); o[2]=f2bf(a.z); o[3]=f2bf(a.w);
  o[4]=f2bf(b.x); o[5]=f2bf(b.y); o[6]=f2bf(b.z); o[7]=f2bf(b.w);
  *(u16x8*)(out+i*8)=o;
}

// -------- strided chunk convert: 101 chunks of 262144 from stride 786432 ---
__global__ __launch_bounds__(256) void cvt_wv(const float* __restrict__ in,
                                              u16* __restrict__ out, long long n8){
  long long idx=(long long)blockIdx.x*256+threadIdx.x;
  if(idx>=n8) return;
  int e=(int)(idx>>15); long long r8=idx&32767;
  const float* p=in+(long long)e*786432+524288+r8*8;
  float4 a=((const float4*)p)[0], b=((const float4*)p)[1];
  u16x8 o;
  o[0]=f2bf(a.x); o[1]=f2bf(a.y); o[2]=f2bf(a.z); o[3]=f2bf(a.w);
  o[4]=f2bf(b.x); o[5]=f2bf(b.y); o[6]=f2bf(b.z); o[7]=f2bf(b.w);
  *(u16x8*)(out+idx*8)=o;
}

// -------- pad-convert rows: [rows,ks] f32 -> [rows,kd] bf16 (zero pad) -----
__global__ __launch_bounds__(256) void cvt_pad(const float* __restrict__ in,
                                               u16* __restrict__ out,
                                               int rows, int ks, int kd){
  long long idx=(long long)blockIdx.x*256+threadIdx.x;
  if(idx>=(long long)rows*kd) return;
  int r=(int)(idx/kd), c=(int)(idx-(long long)r*kd);
  out[idx]=(c<ks)? f2bf(in[(long long)r*ks+c]) : (u16)0;
}

// ---- per (b,e): w = abar@mem_b + pos_e (bf16) — softmax already fused -----
__global__ __launch_bounds__(256) void expert_reduce2(
    const float* __restrict__ abar, const u16* __restrict__ mem,
    const float* __restrict__ pos, u16* __restrict__ wout)
{
  int b=blockIdx.x, e=blockIdx.y;
  int t=threadIdx.x;
  __shared__ float abf[128];
  if(t<128) abf[t]=abar[((long long)(e*32+b))*128+t];
  __syncthreads();
  float c0=0.f, c1=0.f;
  const u16* mb = mem + (long long)b*65536;
  for(int k=0;k<128;++k){
    float a=abf[k];
    c0+=a*bf2f(mb[k*512+t]);
    c1+=a*bf2f(mb[k*512+t+256]);
  }
  c0+=pos[(long long)e*512+t]; c1+=pos[(long long)e*512+t+256];
  u16* o=wout+((long long)e*32+b)*512;
  o[t]=f2bf(c0); o[t+256]=f2bf(c1);
}

// ---------------------------------------------------------------------------
static inline int ceildiv(int a,int b){return (a+b-1)/b;}

static GP mkGP(const u16* A,int lda,long long sA1,long long sA2,
  const u16* B,int ldb,long long sB1,long long sB2,
  const float* bias,long long sb1,long long sb2,
  float* Cf,u16* Cb,int ldc,long long sC1,long long sC2,
  int M,int N,int K,int Z2,int epi,float alpha,long long sbg,int perm){
  GP p;
  p.A=A; p.lda=lda; p.sA1=sA1; p.sA2=sA2;
  p.B=B; p.ldb=ldb; p.sB1=sB1; p.sB2=sB2;
  p.bias=bias; p.sb1=sb1; p.sb2=sb2; p.sbg=sbg;
  p.Cf=Cf; p.Cb=Cb; p.ldc=ldc; p.sC1=sC1; p.sC2=sC2;
  p.M=M; p.N=N; p.K=K; p.Z2=Z2; p.epi=epi; p.perm=perm; p.alpha=alpha;
  return p;
}

static void gemmB(hipStream_t s,
  const u16* A,int lda,long long sA1,long long sA2,
  const u16* B,int ldb,long long sB1,long long sB2,
  const float* bias,long long sb1,long long sb2,
  float* Cf,u16* Cb,int ldc,long long sC1,long long sC2,
  int M,int N,int K,int Z,int Z2,int epi,float alpha,
  long long sbg=1,int perm=0){
  GP p=mkGP(A,lda,sA1,sA2,B,ldb,sB1,sB2,bias,sb1,sb2,Cf,Cb,ldc,sC1,sC2,M,N,K,Z2,epi,alpha,sbg,perm);
  dim3 g(ceildiv(M,128), ceildiv(N,128), Z);
  gemm_bt<<<g, dim3(256), 0, s>>>(p);
}

static void gemmBig(hipStream_t s,
  const u16* A,int lda,long long sA1,long long sA2,
  const u16* B,int ldb,long long sB1,long long sB2,
  const float* bias,long long sb1,long long sb2,
  float* Cf,u16* Cb,int ldc,long long sC1,long long sC2,
  int M,int N,int K,int Z,int Z2,int epi,float alpha){
  GP p=mkGP(A,lda,sA1,sA2,B,ldb,sB1,sB2,bias,sb1,sb2,Cf,Cb,ldc,sC1,sC2,M,N,K,Z2,epi,alpha,1,0);
  dim3 g(ceildiv(M,256), ceildiv(N,256), Z);
  gemm_big8<<<g, dim3(512), 0, s>>>(p);
}

static inline void cvt(hipStream_t s, const float* in, u16* out, long long n){
  long long n8=n/8;
  cvt_bf16<<<(int)((n8+255)/256),256,0,s>>>(in,out,n8);
}

extern "C" void kernel_launch(void* const* d_in, const int* in_sizes, int n_in,
                              void* d_out, int out_size, void* d_ws, size_t ws_size,
                              hipStream_t stream) {
  (void)in_sizes; (void)n_in; (void)out_size;
  const float* poses=(const float*)d_in[0];
  const float* W_in =(const float*)d_in[1];
  const float* b_in =(const float*)d_in[2];
  const float* eq_w =(const float*)d_in[3];
  const float* eq_b =(const float*)d_in[4];
  const float* eo_w =(const float*)d_in[5];
  const float* eo_b =(const float*)d_in[6];
  const float* ef1_w=(const float*)d_in[7];
  const float* ef1_b=(const float*)d_in[8];
  const float* ef2_w=(const float*)d_in[9];
  const float* ef2_b=(const float*)d_in[10];
  const float* en1_g=(const float*)d_in[11];
  const float* en1_b=(const float*)d_in[12];
  const float* en2_g=(const float*)d_in[13];
  const float* en2_b=(const float*)d_in[14];
  const float* c1_w =(const float*)d_in[15];
  const float* c1_b =(const float*)d_in[16];
  const float* c2_w =(const float*)d_in[17];
  const float* c2_b =(const float*)d_in[18];
  const float* mlp_w=(const float*)d_in[19];
  const float* mlp_b=(const float*)d_in[20];
  const float* xp_pos  =(const float*)d_in[21];
  const float* xp_qkv_w=(const float*)d_in[22];
  const float* xp_qkv_b=(const float*)d_in[23];
  const float* xp_o_w  =(const float*)d_in[24];
  const float* xp_o_b  =(const float*)d_in[25];
  const float* xp_n_g  =(const float*)d_in[26];
  const float* xp_n_b  =(const float*)d_in[27];
  const float* xp_l_w  =(const float*)d_in[28];
  const float* xp_l_b  =(const float*)d_in[29];
  const float* fn_g =(const float*)d_in[30];
  const float* fn_b =(const float*)d_in[31];
  const float* hd_w =(const float*)d_in[32];
  const float* hd_b =(const float*)d_in[33];
  float* out=(float*)d_out;

  float* ws=(float*)d_ws;
  size_t off=0;
  auto alloc=[&](size_t n)->float*{ float* p=ws+off; off+=(n+255)&~(size_t)255; return p; };
  float* RA = alloc(137760768);   // encoder-phase / expert-phase union
  float* RB = alloc(84381184);    // persistent converted weights
  float* RC = alloc(5849088);     // cross-phase (gmem, pools, w, cmean)
  if(off*sizeof(float) > ws_size) return;  // ws too small: bail (fails loudly)

  // --- region A: encoder phase ---
  u16* qkvb =(u16*)RA;                   // [16384,1536]
  u16* Sb16 =(u16*)(RA+12582912);        // [32,8,512,512]
  u16* ffb  =(u16*)(RA+46137344);        // [16384,2048]
  u16* ctxb =(u16*)(RA+62914560);        // [16384,512]
  u16* Vtb  =(u16*)(RA+67108864);        // [32*8*64,512]
  float* act0f=RA+71303168;
  float* act1f=RA+79691776;
  float* tmpf =RA+88080384;
  u16* act0b=(u16*)(RA+96468992);
  u16* act1b=(u16*)(RA+98566144);
  // --- region A: expert phase (aliases encoder bufs) ---
  u16* Pb   =(u16*)RA;                   // [101,4096,512] bf16
  float* abarf=RA+105906176;             // [3232,128] f32
  float* U  =RA+132382720;               // [4096,101]
  float* ctx1=RA+132796416;              // [3232,512]
  float* ctx2=RA+134451200;
  u16* ln1b =(u16*)(RA+136105984);       // [3232,512]
  u16* ln2b =(u16*)(RA+136933376);
  // --- region B: weights ---
  u16* posesb=(u16*)RB;                  // [16384,96]
  u16* W_inb =(u16*)(RB+786432);
  u16* eqwb  =(u16*)(RB+811008);
  u16* eowb  =(u16*)(RB+1597440);
  u16* ef1wb =(u16*)(RB+1859584);
  u16* ef2wb =(u16*)(RB+2908160);
  u16* wc1b  =(u16*)(RB+3956736);
  u16* wc2b  =(u16*)(RB+4349952);
  u16* mlpwb =(u16*)(RB+4743168);
  u16* hdwb  =(u16*)(RB+4874240);
  u16* xposb =(u16*)(RB+4899840);
  u16* owb   =(u16*)(RB+4925696);        // [101,512,512]
  u16* lwb   =(u16*)(RB+18163968);
  u16* wvb   =(u16*)(RB+31402240);       // [101,512,512]
  u16* wqkT  =(u16*)(RB+44640512);       // [202,512,512]  z=2e+half (q,k)
  u16* Gpb   =(u16*)(RB+71117056);       // [101,512,512]  G' = Wk^T Wq
  u16* Hb    =(u16*)(RB+84355328);       // [101,512]
  // --- region C ---
  u16* gmemb =(u16*)RC;                  // [4096,512]
  u16* p1b   =(u16*)(RC+1048576);        // [32,256,512]
  u16* membb =(u16*)(RC+3145728);        // [32,128,512]
  u16* wb    =(u16*)(RC+4194304);        // [101,32,512]
  u16* cmeanb=(u16*)(RC+5021696);        // [101,32,512]

  // ---- up-front converts ----
  cvt_pad<<<ceildiv(16384*96,256),256,0,stream>>>(poses,posesb,16384,86,96);
  cvt_pad<<<ceildiv(512*96,256),256,0,stream>>>(W_in,W_inb,512,86,96);
  cvt(stream,eq_w,eqwb,1572864);
  cvt(stream,eo_w,eowb,524288);
  cvt(stream,ef1_w,ef1wb,2097152);
  cvt(stream,ef2_w,ef2wb,2097152);
  cvt(stream,mlp_w,mlpwb,262144);
  cvt(stream,hd_w,hdwb,51200);
  cvt(stream,xp_pos,xposb,51712);
  cvt(stream,xp_o_w,owb,26476544);
  cvt(stream,xp_l_w,lwb,26476544);
  wrepackb<<<ceildiv(512*1536,256),256,0,stream>>>(c1_w,wc1b);
  wrepackb<<<ceildiv(512*1536,256),256,0,stream>>>(c2_w,wc2b);
  trcvtb<<<dim3(8,8,202),256,0,stream>>>(xp_qkv_w,wqkT);
  cvt_wv<<<ceildiv(101*32768,256),256,0,stream>>>(xp_qkv_w,wvb,(long long)101*32768);

  // ---- input projection + positional encoding (scalar epi3 path, R8) ----
  gemmB(stream, posesb,96,0,0, W_inb,96,0,0, b_in,0,0,
        act0f,act0b,512,0,0, 16384,512,96, 1,1, 3,1.f);

  // ---- 2 encoder layers (post-norm), attention batched z=256 ----
  for(int l=0;l<2;++l){
    gemmBig(stream, act0b,512,0,0, eqwb+(long long)l*786432,512,0,0,
          eq_b+(long long)l*1536,0,0, nullptr,qkvb,1536,0,0, 16384,1536,512, 1,1, 0,1.f);
    gemmB(stream, qkvb,1536,786432,64, qkvb+512,1536,786432,64, nullptr,0,0,
          nullptr,Sb16,512,2097152,262144, 512,512,64, 256,8, 0,0.125f);
    softmax512b<<<32768,256,0,stream>>>(Sb16,131072);
    vtransb<<<dim3(8,8,32),256,0,stream>>>(qkvb,Vtb);
    gemmB(stream, Sb16,512,2097152,262144, Vtb,512,262144,32768, nullptr,0,0,
          nullptr,ctxb,512,262144,64, 512,64,512, 256,8, 0,1.f);
    gemmBig(stream, ctxb,512,0,0, eowb+(long long)l*262144,512,0,0,
          eo_b+(long long)l*512,0,0, tmpf,nullptr,512,0,0, 16384,512,512, 1,1, 0,1.f);
    ln512<<<4096,256,0,stream>>>(tmpf,act0f,en1_g+(long long)l*512,en1_b+(long long)l*512,0,
                                 act1f,act1b,16384);
    gemmBig(stream, act1b,512,0,0, ef1wb+(long long)l*1048576,512,0,0,
          ef1_b+(long long)l*2048,0,0, nullptr,ffb,2048,0,0, 16384,2048,512, 1,1, 1,1.f);
    gemmBig(stream, ffb,2048,0,0, ef2wb+(long long)l*1048576,2048,0,0,
          ef2_b+(long long)l*512,0,0, tmpf,nullptr,512,0,0, 16384,512,2048, 1,1, 0,1.f);
    ln512<<<4096,256,0,stream>>>(tmpf,act1f,en2_g+(long long)l*512,en2_b+(long long)l*512,0,
                                 act0f,act0b,16384);
  }

  // ---- temporal pooling: conv-gelu-pool x2, then MLP-gelu ----
  u16* Ccb=(u16*)RA;   // aliases qkvb/Sb16 (encoder attn bufs dead)
  im2col3b<<<(int)(((long long)16384*1536/8+255)/256),256,0,stream>>>(act0b,Ccb,512,(long long)16384*1536/8);
  gemmBig(stream, Ccb,1536,0,0, wc1b,1536,0,0, c1_b,0,0,
        tmpf,nullptr,512,0,0, 16384,512,1536, 1,1, 2,1.f);
  pool2b<<<(int)(((long long)32*256*128+255)/256),256,0,stream>>>(tmpf,p1b,512,(long long)32*256*128);
  im2col3b<<<(int)(((long long)8192*1536/8+255)/256),256,0,stream>>>(p1b,Ccb,256,(long long)8192*1536/8);
  gemmBig(stream, Ccb,1536,0,0, wc2b,1536,0,0, c2_b,0,0,
        tmpf,nullptr,512,0,0, 8192,512,1536, 1,1, 2,1.f);
  pool2b<<<(int)(((long long)32*128*128+255)/256),256,0,stream>>>(tmpf,membb,256,(long long)32*128*128);
  gemmBig(stream, membb,512,0,0, mlpwb,512,0,0, mlp_b,0,0,
        nullptr,gmemb,512,0,0, 4096,512,512, 1,1, 2,1.f);

  // ---- experts (fused S+softmax+colmean) ----
  gemmBig(stream, wqkT+262144,512,524288,0, wqkT,512,524288,0, nullptr,0,0,
        nullptr,Gpb,512,262144,0, 512,512,512, 101,1, 0,1.f);
  gemmB(stream, Gpb,512,262144,0, xposb,512,512,0, nullptr,0,0,
        nullptr,Hb,1,512,0, 512,1,512, 101,1, 0,1.f);
  gemmB(stream, gmemb,512,0,0, Hb,512,0,0, nullptr,0,0,
        U,nullptr,101,0,0, 4096,101,512, 1,1, 0,ALPHA_S);
  gemmBig(stream, gmemb,512,0,0, Gpb,512,262144,0, nullptr,0,0,
        nullptr,Pb,512,2097152,0, 4096,512,512, 101,1, 0,1.f);
  gemm_sfused<<<3232,256,0,stream>>>(Pb, gmemb, U, abarf);
  expert_reduce2<<<dim3(32,101),256,0,stream>>>(abarf,gmemb,xp_pos,wb);
  gemmB(stream, wb,512,16384,0, wvb,512,262144,0, xp_qkv_b+1024,1536,0,
        nullptr,cmeanb,512,16384,0, 32,512,512, 101,1, 0,1.f);

  // ---- tail: proj -> LN -> proj -> LN(fn) -> head (permuted write) ----
  gemmB(stream, cmeanb,512,16384,0, owb,512,262144,0, xp_o_b,512,0,
        ctx1,nullptr,512,16384,0, 32,512,512, 101,1, 0,1.f);
  ln512<<<808,256,0,stream>>>(ctx1,nullptr,xp_n_g,xp_n_b,1, nullptr,ln1b,3232);
  gemmB(stream, ln1b,512,16384,0, lwb,512,262144,0, xp_l_b,512,0,
        ctx2,nullptr,512,16384,0, 32,512,512, 101,1, 0,1.f);
  ln512<<<808,256,0,stream>>>(ctx2,nullptr,fn_g,fn_b,0, nullptr,ln2b,3232);
  gemmB(stream, ln2b,512,0,0, hdwb,512,0,0, hd_b,0,0,
        out,nullptr,100,0,0, 3232,100,512, 1,1, 0,1.f, 1,1);
}